// Round 14
// baseline (305.432 us; speedup 1.0000x reference)
//
#include <hip/hip_runtime.h>
#include <hip/hip_bf16.h>

// Shapes (fixed per reference)
#define BB 8
#define LL 1024
#define EE 1024
#define HH 16
#define DHH 64
#define FFF 4096

typedef __attribute__((ext_vector_type(8))) short short8;
typedef __attribute__((ext_vector_type(4))) float f32x4;

__device__ inline f32x4 mfma16(short8 a, short8 b, f32x4 c) {
    return __builtin_amdgcn_mfma_f32_16x16x32_bf16(a, b, c, 0, 0, 0);
}

__device__ inline void async_ld16(const __hip_bfloat16* g, __hip_bfloat16* l) {
    __builtin_amdgcn_global_load_lds(
        (const __attribute__((address_space(1))) void*)g,
        (__attribute__((address_space(3))) void*)l, 16, 0, 0);
}

__device__ inline unsigned short bf16bits(float f) {
    __hip_bfloat16 h = __float2bfloat16(f);
    return *reinterpret_cast<unsigned short*>(&h);
}

__device__ inline float bf2f(unsigned short u) {
    unsigned v = ((unsigned)u) << 16;
    return *reinterpret_cast<float*>(&v);
}

__device__ inline float exp2_fast(float x) {
    float r;
    asm("v_exp_f32 %0, %1" : "=v"(r) : "v"(x));
    return r;
}

__device__ inline unsigned cvt_pk_bf16(float lo, float hi) {
    unsigned r;
    asm("v_cvt_pk_bf16_f32 %0, %1, %2" : "=v"(r) : "v"(lo), "v"(hi));
    return r;
}

// raw workgroup barrier, memory-fenced, no sched pins (m141: pinning hurts)
__device__ inline void wg_barrier() {
    asm volatile("" ::: "memory");
    __builtin_amdgcn_s_barrier();
    asm volatile("" ::: "memory");
}

// ------ fused weight transpose+convert (all 6 weights) + x f32->bf16 (one launch) ------
__global__ __launch_bounds__(256) void wtrans_all(
    const float* __restrict__ Wq, const float* __restrict__ Wk, const float* __restrict__ Wv,
    const float* __restrict__ Wo, const float* __restrict__ W1, const float* __restrict__ W2,
    const float* __restrict__ x,
    __hip_bfloat16* __restrict__ wqkvt, __hip_bfloat16* __restrict__ wot,
    __hip_bfloat16* __restrict__ w1t, __hip_bfloat16* __restrict__ w2t,
    __hip_bfloat16* __restrict__ xb) {
    const int id = blockIdx.x;
    const int tid = threadIdx.x;
    if (id >= 3072) { // x conversion: 2048 blocks x 1024 float4
        const int xi = id - 3072;
#pragma unroll
        for (int j = 0; j < 4; ++j) {
            const size_t f4 = (size_t)xi * 1024 + j * 256 + tid;
            float4 v = reinterpret_cast<const float4*>(x)[f4];
            ushort4 o;
            o.x = bf16bits(v.x); o.y = bf16bits(v.y); o.z = bf16bits(v.z); o.w = bf16bits(v.w);
            reinterpret_cast<ushort4*>(xb)[f4] = o;
        }
        return;
    }
    const float* src;
    __hip_bfloat16* dst;
    int K, N, k0, n0;
    if (id < 768) { // Wq/Wk/Wv: per-head [1024,64] -> [64,1024], 256 blocks each
        const int which = id >> 8, r = id & 255;
        const int z = r >> 4, xx = r & 15;
        src = ((which == 0) ? Wq : (which == 1) ? Wk : Wv) + (size_t)z * 65536;
        dst = wqkvt + (size_t)which * 1024 * 1024 + (size_t)z * 65536;
        K = 1024; N = 64; k0 = xx * 64; n0 = 0;
    } else if (id < 1024) { // Wo [1024,1024]
        const int r = id - 768;
        src = Wo; dst = wot; K = 1024; N = 1024; k0 = (r & 15) * 64; n0 = (r >> 4) * 64;
    } else if (id < 2048) { // W1 [1024,4096]
        const int r = id - 1024;
        src = W1; dst = w1t; K = 1024; N = 4096; k0 = (r & 15) * 64; n0 = (r >> 4) * 64;
    } else { // W2 [4096,1024]
        const int r = id - 2048;
        src = W2; dst = w2t; K = 4096; N = 1024; k0 = (r & 63) * 64; n0 = (r >> 6) * 64;
    }
    __shared__ __hip_bfloat16 t[64 * 66];
#pragma unroll
    for (int i = 0; i < 16; ++i) {
        int idx = tid + i * 256;
        int kr = idx >> 6, nc = idx & 63;
        t[kr * 66 + nc] = __float2bfloat16(src[(size_t)(k0 + kr) * N + n0 + nc]);
    }
    __syncthreads();
#pragma unroll
    for (int i = 0; i < 16; ++i) {
        int idx = tid + i * 256;
        int nr = idx >> 6, kc = idx & 63;
        dst[(size_t)(n0 + nr) * K + k0 + kc] = t[kc * 66 + nr];
    }
}

// ======= QKV GEMM: 256x128 tile, 768 blocks = 3 exact rounds/CU (balance fix) =======
// 8 waves (2m x 4n), wave tile 128x32, acc[8][2]. BK=64, LDS 96KB (A 64 + B 32).
// 2 segments/K-tile: S0 {MFMA aLo x B; read aHi(t)}; S1 {MFMA aHi x B; lgkm drain;
// stage tile t+2 (6 instrs); vmcnt(6)}; tail after barrier reads t+1.
// bf16 out + 3-range bias + fused V-transpose for cols [2048,3072).
__global__ __launch_bounds__(512, 2) void gemm_qkv(
    const __hip_bfloat16* __restrict__ A, const __hip_bfloat16* __restrict__ Bm,
    int M, int N, int K, void* __restrict__ Cout,
    const float* __restrict__ bias0, const float* __restrict__ bias1,
    const float* __restrict__ bias2, __hip_bfloat16* __restrict__ vtout) {
    __shared__ __hip_bfloat16 Ab[2][2][128 * 64]; // [buf][half][r*64+e]
    __shared__ __hip_bfloat16 Bbf[2][128 * 64];   // [buf][r*64+e]
    const int flat = blockIdx.x + gridDim.x * blockIdx.y; // grid (32,24) = 768
    const int xcd = flat & 7, rank = flat >> 3;           // 96 ranks/XCD
    const int mb = (xcd & 3) * 8 + rank / 12;
    const int nb = (xcd >> 2) * 12 + rank % 12;
    const int m0 = mb * 256, n0 = nb * 128;
    const int tid = threadIdx.x;
    const int wid = tid >> 6, l = tid & 63;
    const int wm = wid >> 2, wn = wid & 3;
    const int lr = l & 15, lg = l >> 4;
    const int T = K >> 6;

    const int c0 = tid, c1 = tid + 512;
    const int r0 = c0 >> 3, s0 = (((c0 & 7) ^ (r0 & 7)) << 3);
    const int r1 = c1 >> 3, s1 = (((c1 & 7) ^ (r1 & 7)) << 3);
    const int ldst0 = wid * 512;
    const int ldst1 = 4096 + wid * 512;

#define STAGE_A(bi, half, kt)                                                              \
    do {                                                                                   \
        const int _br = m0 + (half) * 128;                                                 \
        __hip_bfloat16* _d = &Ab[bi][half][0];                                             \
        async_ld16(A + (size_t)(_br + r0) * K + (size_t)(kt) * 64 + s0, _d + ldst0);       \
        async_ld16(A + (size_t)(_br + r1) * K + (size_t)(kt) * 64 + s1, _d + ldst1);       \
    } while (0)
#define STAGE_B(bi, kt)                                                                    \
    do {                                                                                   \
        __hip_bfloat16* _d = &Bbf[bi][0];                                                  \
        async_ld16(Bm + (size_t)(n0 + r0) * K + (size_t)(kt) * 64 + s0, _d + ldst0);       \
        async_ld16(Bm + (size_t)(n0 + r1) * K + (size_t)(kt) * 64 + s1, _d + ldst1);       \
    } while (0)

    f32x4 acc[8][2];
#pragma unroll
    for (int m = 0; m < 8; ++m)
#pragma unroll
        for (int n = 0; n < 2; ++n) acc[m][n] = (f32x4){0.f, 0.f, 0.f, 0.f};

    short8 aLo[4][2], aHi[4][2], bR[2][2];

#define LDA(dst, bi, m, kh)                                                        \
    do {                                                                           \
        const int _ra = (m) * 16 + lr;                                             \
        const int _sl = ((kh) * 4 + lg) ^ (_ra & 7);                               \
        dst = *reinterpret_cast<const short8*>(&Ab[bi][wm][_ra * 64 + _sl * 8]);   \
    } while (0)
#define LDB(dst, bi, n, kh)                                                        \
    do {                                                                           \
        const int _rb = wn * 32 + (n) * 16 + lr;                                   \
        const int _sl = ((kh) * 4 + lg) ^ (_rb & 7);                               \
        dst = *reinterpret_cast<const short8*>(&Bbf[bi][_rb * 64 + _sl * 8]);      \
    } while (0)

#define RD_ALO(bi)                                  \
    _Pragma("unroll") for (int m = 0; m < 4; ++m) { \
        LDA(aLo[m][0], bi, m, 0);                   \
        LDA(aLo[m][1], bi, m, 1);                   \
    }
#define RD_AHI(bi)                                  \
    _Pragma("unroll") for (int m = 0; m < 4; ++m) { \
        LDA(aHi[m][0], bi, m + 4, 0);               \
        LDA(aHi[m][1], bi, m + 4, 1);               \
    }
#define RD_B(bi)                                    \
    _Pragma("unroll") for (int n = 0; n < 2; ++n) { \
        LDB(bR[n][0], bi, n, 0);                    \
        LDB(bR[n][1], bi, n, 1);                    \
    }
#define MFMA_H(mbase, afr)                                                          \
    __builtin_amdgcn_s_setprio(1);                                                  \
    _Pragma("unroll") for (int m = 0; m < 4; ++m) {                                 \
        _Pragma("unroll") for (int n = 0; n < 2; ++n) {                             \
            acc[(mbase) + m][n] = mfma16(afr[m][0], bR[n][0], acc[(mbase) + m][n]); \
            acc[(mbase) + m][n] = mfma16(afr[m][1], bR[n][1], acc[(mbase) + m][n]); \
        }                                                                           \
    }                                                                               \
    __builtin_amdgcn_s_setprio(0);

    // prologue: tile0 (6) + tile1 (6); vmcnt(6) -> tile0 complete
    STAGE_B(0, 0);
    STAGE_A(0, 0, 0);
    STAGE_A(0, 1, 0);
    STAGE_B(1, 1);
    STAGE_A(1, 0, 1);
    STAGE_A(1, 1, 1);
    asm volatile("s_waitcnt vmcnt(6)" ::: "memory");
    wg_barrier();
    RD_ALO(0);
    RD_B(0);

    for (int t = 0; t < T; ++t) {
        const int cur = t & 1, nxt = cur ^ 1;
        // S0: MFMA aLo x B; read aHi(t)
        MFMA_H(0, aLo);
        RD_AHI(cur);
        wg_barrier(); // A
        // S1: MFMA aHi x B; drain ds reads; stage tile t+2 into cur; counted vmcnt
        MFMA_H(4, aHi);
        asm volatile("s_waitcnt lgkmcnt(0)" ::: "memory");
        if (t + 2 < T) {
            STAGE_B(cur, t + 2);
            STAGE_A(cur, 0, t + 2);
            STAGE_A(cur, 1, t + 2);
            asm volatile("s_waitcnt vmcnt(6)" ::: "memory"); // t+1 complete
        } else if (t + 1 < T) {
            asm volatile("s_waitcnt vmcnt(0)" ::: "memory");
        }
        wg_barrier(); // B (all waves passed vmcnt -> t+1 LDS globally valid)
        if (t + 1 < T) {
            RD_ALO(nxt);
            RD_B(nxt);
        }
    }
#undef STAGE_A
#undef STAGE_B
#undef LDA
#undef LDB
#undef RD_ALO
#undef RD_AHI
#undef RD_B
#undef MFMA_H

    asm volatile("s_waitcnt vmcnt(0)" ::: "memory");
    __syncthreads(); // main-loop LDS dead

    // ---- epilogue: per-wave LDS transpose [16][36] -> bf16 C store + fused V-transpose ----
    float* eb = reinterpret_cast<float*>(&Ab[0][0][0]) + wid * (16 * 36);
    const int erow = l >> 2, ec = l & 3;
    const int rowg = m0 + wm * 128;
    const int colg = n0 + wn * 32;
    float bv[2];
#pragma unroll
    for (int n = 0; n < 2; ++n) {
        const int col = colg + n * 16 + lr;
        const int s = col >> 10;
        const float* bp = (s == 0) ? bias0 : ((s == 1) ? bias1 : bias2);
        bv[n] = bp[col & 1023];
    }
    __hip_bfloat16* Cb = (__hip_bfloat16*)Cout;
#pragma unroll
    for (int m = 0; m < 8; ++m) {
#pragma unroll
        for (int n = 0; n < 2; ++n)
#pragma unroll
            for (int r = 0; r < 4; ++r)
                eb[(lg * 4 + r) * 36 + n * 16 + lr] = acc[m][n][r] + bv[n];
        {
            float4 v0 = *reinterpret_cast<float4*>(&eb[erow * 36 + ec * 8]);
            float4 v1 = *reinterpret_cast<float4*>(&eb[erow * 36 + ec * 8 + 4]);
            uint4 o;
            o.x = cvt_pk_bf16(v0.x, v0.y);
            o.y = cvt_pk_bf16(v0.z, v0.w);
            o.z = cvt_pk_bf16(v1.x, v1.y);
            o.w = cvt_pk_bf16(v1.z, v1.w);
            *reinterpret_cast<uint4*>(&Cb[(size_t)(rowg + m * 16 + erow) * N + colg + ec * 8]) =
                o;
        }
        if (colg >= 2048 && l < 32) {
            const int d = colg - 2048 + l;
            const int bh2 = ((rowg >> 10) << 4) + (d >> 6);
            const int dl = d & 63;
            const int l0 = (rowg & 1023) + m * 16;
            uint4 o0, o1;
            o0.x = cvt_pk_bf16(eb[0 * 36 + l], eb[1 * 36 + l]);
            o0.y = cvt_pk_bf16(eb[2 * 36 + l], eb[3 * 36 + l]);
            o0.z = cvt_pk_bf16(eb[4 * 36 + l], eb[5 * 36 + l]);
            o0.w = cvt_pk_bf16(eb[6 * 36 + l], eb[7 * 36 + l]);
            o1.x = cvt_pk_bf16(eb[8 * 36 + l], eb[9 * 36 + l]);
            o1.y = cvt_pk_bf16(eb[10 * 36 + l], eb[11 * 36 + l]);
            o1.z = cvt_pk_bf16(eb[12 * 36 + l], eb[13 * 36 + l]);
            o1.w = cvt_pk_bf16(eb[14 * 36 + l], eb[15 * 36 + l]);
            __hip_bfloat16* vrow = vtout + ((size_t)bh2 * 64 + dl) * 1024 + l0;
            *reinterpret_cast<uint4*>(vrow) = o0;
            *reinterpret_cast<uint4*>(vrow + 8) = o1;
        }
    }
}

// ========== 256x256 GEMM, 8 waves x 128x64, read-ahead single-barrier phases ==========
// MODE 2: bf16 out + bias + relu. MODE 4: bf16 PARTIAL out (split-K).
template <int MODE, int CM, int CN, int ZX>
__global__ __launch_bounds__(512, 2) void gemm256(
    const __hip_bfloat16* __restrict__ A, const __hip_bfloat16* __restrict__ Bm,
    int M, int N, int K, int ksplit, size_t zstride, void* __restrict__ Cout,
    const float* __restrict__ bias0) {
    __shared__ __hip_bfloat16 lds[2][2][2][128 * 64]; // [buf][op A=0/B=1][half][r*64+e]
    const int flat = blockIdx.x + gridDim.x * (blockIdx.y + gridDim.y * blockIdx.z);
    const int xcd = flat & 7, rank = flat >> 3;
    const int mc = xcd & 3, hc = xcd >> 2;
    const int ml = rank / CN, nl = rank % CN;
    const int mb = mc * CM + ml;
    const int nb = ZX ? nl : (hc * CN + nl);
    const int zb = ZX ? hc : 0;
    const int m0 = mb * 256, n0 = nb * 256;
    const int tid = threadIdx.x;
    const int wid = tid >> 6, l = tid & 63;
    const int wm = wid >> 2, wn = wid & 3;
    const int lr = l & 15, lg = l >> 4;
    const int T = K / (64 * ksplit);
    const int kb = zb * T;

    const int c0 = tid, c1 = tid + 512;
    const int r0 = c0 >> 3, s0 = (((c0 & 7) ^ (r0 & 7)) << 3);
    const int r1 = c1 >> 3, s1 = (((c1 & 7) ^ (r1 & 7)) << 3);
    const int ldst0 = wid * 512;
    const int ldst1 = 4096 + wid * 512;

#define STAGE(bi, isb, half, kt)                                                             \
    do {                                                                                     \
        const __hip_bfloat16* _s = (isb) ? Bm : A;                                           \
        const int _br = ((isb) ? n0 : m0) + (half) * 128;                                    \
        __hip_bfloat16* _d = &lds[bi][isb][half][0];                                         \
        async_ld16(_s + (size_t)(_br + r0) * K + (size_t)(kb + (kt)) * 64 + s0, _d + ldst0); \
        async_ld16(_s + (size_t)(_br + r1) * K + (size_t)(kb + (kt)) * 64 + s1, _d + ldst1); \
    } while (0)

    f32x4 acc[8][4];
#pragma unroll
    for (int m = 0; m < 8; ++m)
#pragma unroll
        for (int n = 0; n < 4; ++n) acc[m][n] = (f32x4){0.f, 0.f, 0.f, 0.f};

    short8 aLo[4][2], aHi[4][2], bR[4][2];

#define LDA(dst, bi, m, kh)                                                          \
    do {                                                                             \
        const int _ra = (m) * 16 + lr;                                               \
        const int _sl = ((kh) * 4 + lg) ^ (_ra & 7);                                 \
        dst = *reinterpret_cast<const short8*>(&lds[bi][0][wm][_ra * 64 + _sl * 8]); \
    } while (0)
#define LDB(dst, bi, n, kh)                                                               \
    do {                                                                                  \
        const int _rb = (wn & 1) * 64 + (n) * 16 + lr;                                    \
        const int _sl = ((kh) * 4 + lg) ^ (_rb & 7);                                      \
        dst = *reinterpret_cast<const short8*>(&lds[bi][1][wn >> 1][_rb * 64 + _sl * 8]); \
    } while (0)

#define RD_ALO(bi)                      \
    _Pragma("unroll") for (int m = 0; m < 4; ++m) { \
        LDA(aLo[m][0], bi, m, 0);       \
        LDA(aLo[m][1], bi, m, 1);       \
    }
#define RD_AHI(bi)                      \
    _Pragma("unroll") for (int m = 0; m < 4; ++m) { \
        LDA(aHi[m][0], bi, m + 4, 0);   \
        LDA(aHi[m][1], bi, m + 4, 1);   \
    }
#define RD_B01(bi)                      \
    _Pragma("unroll") for (int n = 0; n < 2; ++n) { \
        LDB(bR[n][0], bi, n, 0);        \
        LDB(bR[n][1], bi, n, 1);        \
    }
#define RD_B23(bi)                      \
    _Pragma("unroll") for (int n = 2; n < 4; ++n) { \
        LDB(bR[n][0], bi, n, 0);        \
        LDB(bR[n][1], bi, n, 1);        \
    }
#define MFMA_Q(mbase, afr, nlo)                                            \
    __builtin_amdgcn_s_setprio(1);                                         \
    _Pragma("unroll") for (int m = 0; m < 4; ++m) {                        \
        _Pragma("unroll") for (int n = (nlo); n < (nlo) + 2; ++n) {        \
            acc[(mbase) + m][n] = mfma16(afr[m][0], bR[n][0], acc[(mbase) + m][n]); \
            acc[(mbase) + m][n] = mfma16(afr[m][1], bR[n][1], acc[(mbase) + m][n]); \
        }                                                                  \
    }                                                                      \
    __builtin_amdgcn_s_setprio(0);

    STAGE(0, 1, 0, 0);
    STAGE(0, 1, 1, 0);
    STAGE(0, 0, 0, 0);
    STAGE(0, 0, 1, 0);
    if (T > 1) {
        STAGE(1, 1, 0, 1);
        STAGE(1, 1, 1, 1);
        STAGE(1, 0, 0, 1);
        asm volatile("s_waitcnt vmcnt(6)" ::: "memory"); // tile0 (oldest 8) done
    } else {
        asm volatile("s_waitcnt vmcnt(0)" ::: "memory");
    }
    wg_barrier();
    RD_ALO(0);
    RD_B01(0);

    for (int t = 0; t < T; ++t) {
        const int cur = t & 1, nxt = cur ^ 1;
        wg_barrier(); // A
        MFMA_Q(0, aLo, 0);
        RD_B23(cur);
        if (t + 1 < T) STAGE(nxt, 0, 1, t + 1);
        wg_barrier(); // B
        MFMA_Q(0, aLo, 2);
        RD_AHI(cur);
        if (t + 2 < T) STAGE(cur, 1, 0, t + 2);
        wg_barrier(); // C
        MFMA_Q(4, aHi, 0);
        if (t + 2 < T) {
            asm volatile("s_waitcnt vmcnt(2)" ::: "memory");
            STAGE(cur, 1, 1, t + 2);
            STAGE(cur, 0, 0, t + 2);
        } else if (t + 1 < T) {
            asm volatile("s_waitcnt vmcnt(0)" ::: "memory");
        }
        wg_barrier(); // D
        MFMA_Q(4, aHi, 2);
        if (t + 1 < T) {
            RD_ALO(nxt);
            RD_B01(nxt);
        }
    }
#undef STAGE
#undef LDA
#undef LDB
#undef RD_ALO
#undef RD_AHI
#undef RD_B01
#undef RD_B23
#undef MFMA_Q

    asm volatile("s_waitcnt vmcnt(0)" ::: "memory");
    __syncthreads(); // main-loop LDS dead

    // ---- epilogue: per-wave LDS transpose [16][68] -> full-line bf16 stores ----
    float* eb = reinterpret_cast<float*>(&lds[0][0][0][0]) + wid * (16 * 68);
    const int erow = l >> 3, ec = l & 7;
    const int rowg = m0 + wm * 128;
    const int colg = n0 + wn * 64;
    float bv[4];
#pragma unroll
    for (int n = 0; n < 4; ++n) {
        if constexpr (MODE == 2) {
            bv[n] = bias0[colg + n * 16 + lr];
        } else {
            bv[n] = 0.f;
        }
    }
    __hip_bfloat16* Cb = (MODE == 4)
        ? ((__hip_bfloat16*)Cout + (size_t)zb * zstride)
        : (__hip_bfloat16*)Cout;
#pragma unroll
    for (int m = 0; m < 8; ++m) {
#pragma unroll
        for (int n = 0; n < 4; ++n)
#pragma unroll
            for (int r = 0; r < 4; ++r) {
                float v = acc[m][n][r] + bv[n];
                if constexpr (MODE == 2) v = fmaxf(v, 0.f);
                eb[(lg * 4 + r) * 68 + n * 16 + lr] = v;
            }
#pragma unroll
        for (int i = 0; i < 2; ++i) {
            const int rr = erow + i * 8;
            float4 v0 = *reinterpret_cast<float4*>(&eb[rr * 68 + ec * 8]);
            float4 v1 = *reinterpret_cast<float4*>(&eb[rr * 68 + ec * 8 + 4]);
            uint4 o;
            o.x = cvt_pk_bf16(v0.x, v0.y);
            o.y = cvt_pk_bf16(v0.z, v0.w);
            o.z = cvt_pk_bf16(v1.x, v1.y);
            o.w = cvt_pk_bf16(v1.z, v1.w);
            *reinterpret_cast<uint4*>(&Cb[(size_t)(rowg + m * 16 + rr) * N + colg + ec * 8]) = o;
        }
    }
}

// -------- flash attention v4: 32 q-rows/wave, swapped QK^T, in-register softmax --------
__global__ __launch_bounds__(512, 4) void attn4(const __hip_bfloat16* __restrict__ qkv,
                                                const __hip_bfloat16* __restrict__ vt,
                                                __hip_bfloat16* __restrict__ cat) {
    const int orig = blockIdx.y * 4 + blockIdx.x; // gridDim (4,128), nwg 512
    const int swz = (orig & 7) * 64 + (orig >> 3); // XCD -> 16 consecutive bh
    const int qt = swz & 3, bh = swz >> 2;
    const int b = bh >> 4, h = bh & 15;
    const int tid = threadIdx.x, w = tid >> 6, l = tid & 63;
    const int lr = l & 15, lg = l >> 4;
    const int sw = lr & 7;

    __shared__ __hip_bfloat16 Ks[2][64 * 64];
    __shared__ __hip_bfloat16 Vs[2][64 * 64];
    __shared__ __hip_bfloat16 plds[8][32 * 72];

    short8 qa[2][2];
#pragma unroll
    for (int q = 0; q < 2; ++q) {
        const size_t qrow = (size_t)(b * LL + qt * 256 + w * 32 + q * 16 + lr);
        qa[q][0] = *reinterpret_cast<const short8*>(qkv + qrow * 3072 + h * 64 + lg * 8);
        qa[q][1] = *reinterpret_cast<const short8*>(qkv + qrow * 3072 + h * 64 + 32 + lg * 8);
    }

    const int rA = tid >> 3, sA = (((tid & 7) ^ (rA & 7)) << 3);
    const __hip_bfloat16* kg = qkv + (size_t)(b * LL + rA) * 3072 + 1024 + h * 64 + sA;
    const __hip_bfloat16* vg = vt + ((size_t)bh * 64 + rA) * LL + sA;

#define STAGE_KV(bi, k0)                                        \
    do {                                                        \
        async_ld16(kg + (size_t)(k0) * 3072, &Ks[bi][w * 512]); \
        async_ld16(vg + (k0), &Vs[bi][w * 512]);                \
    } while (0)

    float mrun[2] = {-INFINITY, -INFINITY}, lrun[2] = {0.f, 0.f};
    f32x4 oacc[2][4];
#pragma unroll
    for (int q = 0; q < 2; ++q)
#pragma unroll
        for (int n = 0; n < 4; ++n) oacc[q][n] = (f32x4){0.f, 0.f, 0.f, 0.f};

    STAGE_KV(0, 0);
    asm volatile("s_waitcnt vmcnt(0)" ::: "memory");
    __syncthreads();

    const float SCALE = 0.18033688011112042f; // 1/sqrt(64) * log2(e)

    int cur = 0;
    for (int kt = 0; kt < 16; ++kt) {
        if (kt < 15) STAGE_KV(cur ^ 1, (kt + 1) * 64);

        f32x4 s[2][4];
#pragma unroll
        for (int m = 0; m < 4; ++m) {
            const int krow = m * 16 + lr;
            const short8 kf0 =
                *reinterpret_cast<const short8*>(&Ks[cur][krow * 64 + ((lg ^ sw) << 3)]);
            const short8 kf1 =
                *reinterpret_cast<const short8*>(&Ks[cur][krow * 64 + (((lg + 4) ^ sw) << 3)]);
#pragma unroll
            for (int q = 0; q < 2; ++q) {
                f32x4 t = (f32x4){0.f, 0.f, 0.f, 0.f};
                t = mfma16(kf0, qa[q][0], t);
                t = mfma16(kf1, qa[q][1], t);
                s[q][m] = t * SCALE;
            }
        }
        float smax[2];
#pragma unroll
        for (int q = 0; q < 2; ++q) {
            float mx = s[q][0][0];
#pragma unroll
            for (int m = 0; m < 4; ++m)
#pragma unroll
                for (int r = 0; r < 4; ++r) mx = fmaxf(mx, s[q][m][r]);
            mx = fmaxf(mx, __shfl_xor(mx, 16, 64));
            mx = fmaxf(mx, __shfl_xor(mx, 32, 64));
            smax[q] = mx;
        }
        if (__any(fmaxf(smax[0] - mrun[0], smax[1] - mrun[1]) > 8.0f)) {
#pragma unroll
            for (int q = 0; q < 2; ++q) {
                const float mnew = fmaxf(mrun[q], smax[q]);
                const float alpha = exp2_fast(mrun[q] - mnew);
                mrun[q] = mnew;
                lrun[q] *= alpha;
#pragma unroll
                for (int r = 0; r < 4; ++r) {
                    const float aD = __shfl(alpha, lg * 4 + r, 64);
#pragma unroll
                    for (int n = 0; n < 4; ++n) oacc[q][n][r] *= aD;
                }
            }
        }
#pragma unroll
        for (int q = 0; q < 2; ++q) {
            float tsum = 0.f;
#pragma unroll
            for (int m = 0; m < 4; ++m) {
                float p0 = exp2_fast(s[q][m][0] - mrun[q]);
                float p1 = exp2_fast(s[q][m][1] - mrun[q]);
                float p2 = exp2_fast(s[q][m][2] - mrun[q]);
                float p3 = exp2_fast(s[q][m][3] - mrun[q]);
                tsum += (p0 + p1) + (p2 + p3);
                uint2 d;
                d.x = cvt_pk_bf16(p0, p1);
                d.y = cvt_pk_bf16(p2, p3);
                *reinterpret_cast<uint2*>(&plds[w][(q * 16 + lr) * 72 + m * 16 + lg * 4]) = d;
            }
            tsum += __shfl_xor(tsum, 16, 64);
            tsum += __shfl_xor(tsum, 32, 64);
            lrun[q] += tsum;
        }
        asm volatile("s_waitcnt lgkmcnt(0)" ::: "memory");
        __builtin_amdgcn_sched_barrier(0);

        short8 pa[2][2];
#pragma unroll
        for (int q = 0; q < 2; ++q) {
            pa[q][0] = *reinterpret_cast<const short8*>(&plds[w][(q * 16 + lr) * 72 + lg * 8]);
            pa[q][1] =
                *reinterpret_cast<const short8*>(&plds[w][(q * 16 + lr) * 72 + 32 + lg * 8]);
        }
#pragma unroll
        for (int n = 0; n < 4; ++n) {
            const int vrow = n * 16 + lr;
            const short8 vf0 =
                *reinterpret_cast<const short8*>(&Vs[cur][vrow * 64 + ((lg ^ sw) << 3)]);
            const short8 vf1 =
                *reinterpret_cast<const short8*>(&Vs[cur][vrow * 64 + (((lg + 4) ^ sw) << 3)]);
#pragma unroll
            for (int q = 0; q < 2; ++q) {
                oacc[q][n] = mfma16(pa[q][0], vf0, oacc[q][n]);
                oacc[q][n] = mfma16(pa[q][1], vf1, oacc[q][n]);
            }
        }

        asm volatile("s_waitcnt vmcnt(0)" ::: "memory");
        __syncthreads();
        cur ^= 1;
    }
#undef STAGE_KV

#pragma unroll
    for (int q = 0; q < 2; ++q) {
        float rinv[4];
#pragma unroll
        for (int r = 0; r < 4; ++r) rinv[r] = 1.0f / __shfl(lrun[q], lg * 4 + r, 64);
#pragma unroll
        for (int n = 0; n < 4; ++n)
#pragma unroll
            for (int r = 0; r < 4; ++r) {
                const float v = oacc[q][n][r] * rinv[r];
                cat[(size_t)(b * LL + qt * 256 + w * 32 + q * 16 + lg * 4 + r) * EE + h * 64 +
                    n * 16 + lr] = __float2bfloat16(v);
            }
    }
}

// ------- fused split-K reduce (bf16 partials) + residual + bias + LayerNorm (E=1024) -------
template <bool CBF16, bool OUTF32>
__global__ __launch_bounds__(256) void ln_fused(const __hip_bfloat16* __restrict__ a,
                                                const __hip_bfloat16* __restrict__ b,
                                                const void* __restrict__ cv,
                                                const float* __restrict__ colbias,
                                                const float* __restrict__ gamma,
                                                const float* __restrict__ beta,
                                                void* __restrict__ outv) {
    const int row = blockIdx.x, tid = threadIdx.x;
    const size_t base = (size_t)row * EE;
    const ushort4 ua = reinterpret_cast<const ushort4*>(a + base)[tid];
    const ushort4 ub = reinterpret_cast<const ushort4*>(b + base)[tid];
    float4 z;
    if constexpr (CBF16) {
        const ushort4 uc =
            reinterpret_cast<const ushort4*>((const __hip_bfloat16*)cv + base)[tid];
        z.x = bf2f(uc.x); z.y = bf2f(uc.y); z.z = bf2f(uc.z); z.w = bf2f(uc.w);
    } else {
        z = reinterpret_cast<const float4*>((const float*)cv + base)[tid];
    }
    float4 cb = reinterpret_cast<const float4*>(colbias)[tid];
    float4 x;
    x.x = bf2f(ua.x) + bf2f(ub.x) + z.x + cb.x;
    x.y = bf2f(ua.y) + bf2f(ub.y) + z.y + cb.y;
    x.z = bf2f(ua.z) + bf2f(ub.z) + z.z + cb.z;
    x.w = bf2f(ua.w) + bf2f(ub.w) + z.w + cb.w;
    float s = x.x + x.y + x.z + x.w;
    float s2 = x.x * x.x + x.y * x.y + x.z * x.z + x.w * x.w;
#pragma unroll
    for (int msk = 1; msk < 64; msk <<= 1) {
        s += __shfl_xor(s, msk, 64);
        s2 += __shfl_xor(s2, msk, 64);
    }
    __shared__ float red[8];
    const int w = tid >> 6, l = tid & 63;
    if (l == 0) { red[w] = s; red[4 + w] = s2; }
    __syncthreads();
    s = red[0] + red[1] + red[2] + red[3];
    s2 = red[4] + red[5] + red[6] + red[7];
    const float mean = s * (1.f / 1024.f);
    const float var = s2 * (1.f / 1024.f) - mean * mean;
    const float rstd = rsqrtf(var + 1e-10f);
    float4 g = reinterpret_cast<const float4*>(gamma)[tid];
    float4 bt = reinterpret_cast<const float4*>(beta)[tid];
    float4 o;
    o.x = g.x * (x.x - mean) * rstd + bt.x;
    o.y = g.y * (x.y - mean) * rstd + bt.y;
    o.z = g.z * (x.z - mean) * rstd + bt.z;
    o.w = g.w * (x.w - mean) * rstd + bt.w;
    if constexpr (OUTF32) {
        reinterpret_cast<float4*>((float*)outv + base)[tid] = o;
    } else {
        ushort4 ob;
        ob.x = bf16bits(o.x); ob.y = bf16bits(o.y); ob.z = bf16bits(o.z); ob.w = bf16bits(o.w);
        reinterpret_cast<ushort4*>((__hip_bfloat16*)outv + base)[tid] = ob;
    }
}

extern "C" void kernel_launch(void* const* d_in, const int* in_sizes, int n_in,
                              void* d_out, int out_size, void* d_ws, size_t ws_size,
                              hipStream_t stream) {
    const float* x = (const float*)d_in[0];
    const float* Wq = (const float*)d_in[1];
    const float* bq = (const float*)d_in[2];
    const float* Wk = (const float*)d_in[3];
    const float* bk = (const float*)d_in[4];
    const float* Wv = (const float*)d_in[5];
    const float* bv = (const float*)d_in[6];
    const float* Wo = (const float*)d_in[7];
    const float* bo = (const float*)d_in[8];
    const float* W1 = (const float*)d_in[9];
    const float* b1 = (const float*)d_in[10];
    const float* W2 = (const float*)d_in[11];
    const float* b2 = (const float*)d_in[12];
    const float* gamma1 = (const float*)d_in[13];
    const float* beta1 = (const float*)d_in[14];
    const float* gamma2 = (const float*)d_in[15];
    const float* beta2 = (const float*)d_in[16];
    float* out = (float*)d_out;

    char* Wb = (char*)d_ws;
    const size_t MB = (size_t)1 << 20;
    if (ws_size < 168 * MB) return;
    __hip_bfloat16* xb = (__hip_bfloat16*)(Wb + 0 * MB);
    __hip_bfloat16* wqkvt = (__hip_bfloat16*)(Wb + 16 * MB);
    __hip_bfloat16* wot = (__hip_bfloat16*)(Wb + 22 * MB);
    __hip_bfloat16* w1t = (__hip_bfloat16*)(Wb + 24 * MB);
    __hip_bfloat16* w2t = (__hip_bfloat16*)(Wb + 32 * MB);
    __hip_bfloat16* qkvb = (__hip_bfloat16*)(Wb + 40 * MB);
    __hip_bfloat16* vtb = (__hip_bfloat16*)(Wb + 88 * MB);
    __hip_bfloat16* catb = (__hip_bfloat16*)(Wb + 104 * MB);
    __hip_bfloat16* p0 = (__hip_bfloat16*)(Wb + 40 * MB); // outproj bf16 partials (2x16MB)
    __hip_bfloat16* out2b = (__hip_bfloat16*)(Wb + 136 * MB);
    __hip_bfloat16* hbuf = (__hip_bfloat16*)(Wb + 40 * MB); // FFN1 out (64 MB)
    __hip_bfloat16* q0 = (__hip_bfloat16*)(Wb + 0 * MB);    // FFN2 bf16 partials (2x16MB)
    const size_t PSTRIDE = (size_t)8192 * 1024;             // bf16 elements (16 MB)

    // weights transpose + x conversion, one launch
    wtrans_all<<<5120, 256, 0, stream>>>(Wq, Wk, Wv, Wo, W1, W2, x, wqkvt, wot, w1t, w2t, xb);
    // QKV projection (+ fused V-transpose): 256x128 tiles, 768 blocks = 3 exact rounds
    gemm_qkv<<<dim3(32, 24), 512, 0, stream>>>(xb, wqkvt, 8192, 3072, 1024, qkvb, bq, bk, bv,
                                               vtb);
    // attention v4: 256 q-rows/block
    attn4<<<dim3(4, 128), 512, 0, stream>>>(qkvb, vtb, catb);
    // output projection: split-K=2; per-XCD cluster 8m x 4n, K-half from xcd
    gemm256<4, 8, 4, 1><<<dim3(32, 4, 2), 512, 0, stream>>>(catb, wot, 8192, 1024, 1024, 2,
                                                            PSTRIDE, p0, nullptr);
    // LN1 = LN(p0 + p1 + x + bo) -> bf16 only
    ln_fused<false, false><<<8192, 256, 0, stream>>>(p0, p0 + PSTRIDE, x, bo, gamma1, beta1,
                                                     out2b);
    // FFN1 + ReLU: grid 32x16, per-XCD cluster 8m x 8n
    gemm256<2, 8, 8, 0><<<dim3(32, 16, 1), 512, 0, stream>>>(out2b, w1t, 8192, 4096, 1024, 1, 0,
                                                             hbuf, b1);
    // FFN2: split-K=2; per-XCD cluster 8m x 4n, K-half from xcd
    gemm256<4, 8, 4, 1><<<dim3(32, 4, 2), 512, 0, stream>>>(hbuf, w2t, 8192, 1024, 4096, 2,
                                                            PSTRIDE, q0, nullptr);
    // LN2 = LN(q0 + q1 + out2(bf16) + b2) -> d_out (f32)
    ln_fused<true, true><<<8192, 256, 0, stream>>>(q0, q0 + PSTRIDE, out2b, b2, gamma2, beta2,
                                                   out);
}

// Round 15
// 298.174 us; speedup vs baseline: 1.0243x; 1.0243x over previous
//
#include <hip/hip_runtime.h>
#include <hip/hip_bf16.h>

// Shapes (fixed per reference)
#define BB 8
#define LL 1024
#define EE 1024
#define HH 16
#define DHH 64
#define FFF 4096

typedef __attribute__((ext_vector_type(8))) short short8;
typedef __attribute__((ext_vector_type(4))) float f32x4;

__device__ inline f32x4 mfma16(short8 a, short8 b, f32x4 c) {
    return __builtin_amdgcn_mfma_f32_16x16x32_bf16(a, b, c, 0, 0, 0);
}

__device__ inline void async_ld16(const __hip_bfloat16* g, __hip_bfloat16* l) {
    __builtin_amdgcn_global_load_lds(
        (const __attribute__((address_space(1))) void*)g,
        (__attribute__((address_space(3))) void*)l, 16, 0, 0);
}

__device__ inline unsigned short bf16bits(float f) {
    __hip_bfloat16 h = __float2bfloat16(f);
    return *reinterpret_cast<unsigned short*>(&h);
}

__device__ inline float bf2f(unsigned short u) {
    unsigned v = ((unsigned)u) << 16;
    return *reinterpret_cast<float*>(&v);
}

__device__ inline float exp2_fast(float x) {
    float r;
    asm("v_exp_f32 %0, %1" : "=v"(r) : "v"(x));
    return r;
}

__device__ inline unsigned cvt_pk_bf16(float lo, float hi) {
    unsigned r;
    asm("v_cvt_pk_bf16_f32 %0, %1, %2" : "=v"(r) : "v"(lo), "v"(hi));
    return r;
}

// raw workgroup barrier, memory-fenced, no sched pins (m141: pinning hurts)
__device__ inline void wg_barrier() {
    asm volatile("" ::: "memory");
    __builtin_amdgcn_s_barrier();
    asm volatile("" ::: "memory");
}

// ------ fused weight transpose+convert (all 6 weights) + x f32->bf16 (one launch) ------
__global__ __launch_bounds__(256) void wtrans_all(
    const float* __restrict__ Wq, const float* __restrict__ Wk, const float* __restrict__ Wv,
    const float* __restrict__ Wo, const float* __restrict__ W1, const float* __restrict__ W2,
    const float* __restrict__ x,
    __hip_bfloat16* __restrict__ wqkvt, __hip_bfloat16* __restrict__ wot,
    __hip_bfloat16* __restrict__ w1t, __hip_bfloat16* __restrict__ w2t,
    __hip_bfloat16* __restrict__ xb) {
    const int id = blockIdx.x;
    const int tid = threadIdx.x;
    if (id >= 3072) { // x conversion: 2048 blocks x 1024 float4
        const int xi = id - 3072;
#pragma unroll
        for (int j = 0; j < 4; ++j) {
            const size_t f4 = (size_t)xi * 1024 + j * 256 + tid;
            float4 v = reinterpret_cast<const float4*>(x)[f4];
            ushort4 o;
            o.x = bf16bits(v.x); o.y = bf16bits(v.y); o.z = bf16bits(v.z); o.w = bf16bits(v.w);
            reinterpret_cast<ushort4*>(xb)[f4] = o;
        }
        return;
    }
    const float* src;
    __hip_bfloat16* dst;
    int K, N, k0, n0;
    if (id < 768) { // Wq/Wk/Wv: per-head [1024,64] -> [64,1024], 256 blocks each
        const int which = id >> 8, r = id & 255;
        const int z = r >> 4, xx = r & 15;
        src = ((which == 0) ? Wq : (which == 1) ? Wk : Wv) + (size_t)z * 65536;
        dst = wqkvt + (size_t)which * 1024 * 1024 + (size_t)z * 65536;
        K = 1024; N = 64; k0 = xx * 64; n0 = 0;
    } else if (id < 1024) { // Wo [1024,1024]
        const int r = id - 768;
        src = Wo; dst = wot; K = 1024; N = 1024; k0 = (r & 15) * 64; n0 = (r >> 4) * 64;
    } else if (id < 2048) { // W1 [1024,4096]
        const int r = id - 1024;
        src = W1; dst = w1t; K = 1024; N = 4096; k0 = (r & 15) * 64; n0 = (r >> 4) * 64;
    } else { // W2 [4096,1024]
        const int r = id - 2048;
        src = W2; dst = w2t; K = 4096; N = 1024; k0 = (r & 63) * 64; n0 = (r >> 6) * 64;
    }
    __shared__ __hip_bfloat16 t[64 * 66];
#pragma unroll
    for (int i = 0; i < 16; ++i) {
        int idx = tid + i * 256;
        int kr = idx >> 6, nc = idx & 63;
        t[kr * 66 + nc] = __float2bfloat16(src[(size_t)(k0 + kr) * N + n0 + nc]);
    }
    __syncthreads();
#pragma unroll
    for (int i = 0; i < 16; ++i) {
        int idx = tid + i * 256;
        int nr = idx >> 6, kc = idx & 63;
        dst[(size_t)(n0 + nr) * K + k0 + kc] = t[kc * 66 + nr];
    }
}

// ========== 256x256 GEMM, 8 waves x 128x64, read-ahead single-barrier phases ==========
// MODE 0: bf16 out + 3-range bias (QKV) + fused V-transpose into vtout.
// MODE 2: bf16 out + bias + relu. MODE 4: bf16 PARTIAL out (split-K).
// Staging per tile t: S0 -> Ah1(t+1); S1 -> Bh0(t+2); S2 -> vmcnt(2: tile t+1
// complete, FIFO oldest-8 of <=10) + Bh1+Ah0(t+2); S3 -> reads of t+1 (after
// barrier D => all waves passed vmcnt).
template <int MODE, int CM, int CN, int ZX>
__global__ __launch_bounds__(512, 2) void gemm256(
    const __hip_bfloat16* __restrict__ A, const __hip_bfloat16* __restrict__ Bm,
    int M, int N, int K, int ksplit, size_t zstride, void* __restrict__ Cout,
    const float* __restrict__ bias0, const float* __restrict__ bias1,
    const float* __restrict__ bias2, __hip_bfloat16* __restrict__ vtout) {
    __shared__ __hip_bfloat16 lds[2][2][2][128 * 64]; // [buf][op A=0/B=1][half][r*64+e]
    const int flat = blockIdx.x + gridDim.x * (blockIdx.y + gridDim.y * blockIdx.z);
    const int xcd = flat & 7, rank = flat >> 3;
    const int mc = xcd & 3, hc = xcd >> 2;
    const int ml = rank / CN, nl = rank % CN;
    const int mb = mc * CM + ml;
    const int nb = ZX ? nl : (hc * CN + nl);
    const int zb = ZX ? hc : 0;
    const int m0 = mb * 256, n0 = nb * 256;
    const int tid = threadIdx.x;
    const int wid = tid >> 6, l = tid & 63;
    const int wm = wid >> 2, wn = wid & 3;
    const int lr = l & 15, lg = l >> 4;
    const int T = K / (64 * ksplit);
    const int kb = zb * T;

    const int c0 = tid, c1 = tid + 512;
    const int r0 = c0 >> 3, s0 = (((c0 & 7) ^ (r0 & 7)) << 3);
    const int r1 = c1 >> 3, s1 = (((c1 & 7) ^ (r1 & 7)) << 3);
    const int ldst0 = wid * 512;
    const int ldst1 = 4096 + wid * 512;

#define STAGE(bi, isb, half, kt)                                                             \
    do {                                                                                     \
        const __hip_bfloat16* _s = (isb) ? Bm : A;                                           \
        const int _br = ((isb) ? n0 : m0) + (half) * 128;                                    \
        __hip_bfloat16* _d = &lds[bi][isb][half][0];                                         \
        async_ld16(_s + (size_t)(_br + r0) * K + (size_t)(kb + (kt)) * 64 + s0, _d + ldst0); \
        async_ld16(_s + (size_t)(_br + r1) * K + (size_t)(kb + (kt)) * 64 + s1, _d + ldst1); \
    } while (0)

    f32x4 acc[8][4];
#pragma unroll
    for (int m = 0; m < 8; ++m)
#pragma unroll
        for (int n = 0; n < 4; ++n) acc[m][n] = (f32x4){0.f, 0.f, 0.f, 0.f};

    short8 aLo[4][2], aHi[4][2], bR[4][2];

#define LDA(dst, bi, m, kh)                                                          \
    do {                                                                             \
        const int _ra = (m) * 16 + lr;                                               \
        const int _sl = ((kh) * 4 + lg) ^ (_ra & 7);                                 \
        dst = *reinterpret_cast<const short8*>(&lds[bi][0][wm][_ra * 64 + _sl * 8]); \
    } while (0)
#define LDB(dst, bi, n, kh)                                                               \
    do {                                                                                  \
        const int _rb = (wn & 1) * 64 + (n) * 16 + lr;                                    \
        const int _sl = ((kh) * 4 + lg) ^ (_rb & 7);                                      \
        dst = *reinterpret_cast<const short8*>(&lds[bi][1][wn >> 1][_rb * 64 + _sl * 8]); \
    } while (0)

#define RD_ALO(bi)                      \
    _Pragma("unroll") for (int m = 0; m < 4; ++m) { \
        LDA(aLo[m][0], bi, m, 0);       \
        LDA(aLo[m][1], bi, m, 1);       \
    }
#define RD_AHI(bi)                      \
    _Pragma("unroll") for (int m = 0; m < 4; ++m) { \
        LDA(aHi[m][0], bi, m + 4, 0);   \
        LDA(aHi[m][1], bi, m + 4, 1);   \
    }
#define RD_B01(bi)                      \
    _Pragma("unroll") for (int n = 0; n < 2; ++n) { \
        LDB(bR[n][0], bi, n, 0);        \
        LDB(bR[n][1], bi, n, 1);        \
    }
#define RD_B23(bi)                      \
    _Pragma("unroll") for (int n = 2; n < 4; ++n) { \
        LDB(bR[n][0], bi, n, 0);        \
        LDB(bR[n][1], bi, n, 1);        \
    }
#define MFMA_Q(mbase, afr, nlo)                                            \
    __builtin_amdgcn_s_setprio(1);                                         \
    _Pragma("unroll") for (int m = 0; m < 4; ++m) {                        \
        _Pragma("unroll") for (int n = (nlo); n < (nlo) + 2; ++n) {        \
            acc[(mbase) + m][n] = mfma16(afr[m][0], bR[n][0], acc[(mbase) + m][n]); \
            acc[(mbase) + m][n] = mfma16(afr[m][1], bR[n][1], acc[(mbase) + m][n]); \
        }                                                                  \
    }                                                                      \
    __builtin_amdgcn_s_setprio(0);

    // prologue: tile0 (Bh0,Bh1,Ah0,Ah1) + tile1's Bh0,Bh1,Ah0 = 14 load-instrs
    STAGE(0, 1, 0, 0);
    STAGE(0, 1, 1, 0);
    STAGE(0, 0, 0, 0);
    STAGE(0, 0, 1, 0);
    if (T > 1) {
        STAGE(1, 1, 0, 1);
        STAGE(1, 1, 1, 1);
        STAGE(1, 0, 0, 1);
        asm volatile("s_waitcnt vmcnt(6)" ::: "memory"); // tile0 (oldest 8) done
    } else {
        asm volatile("s_waitcnt vmcnt(0)" ::: "memory");
    }
    wg_barrier();
    RD_ALO(0);
    RD_B01(0);

    for (int t = 0; t < T; ++t) {
        const int cur = t & 1, nxt = cur ^ 1;
        wg_barrier(); // A
        // S0: q00 (aLo x b01); read b23(t); stage Ah1(t+1)
        MFMA_Q(0, aLo, 0);
        RD_B23(cur);
        if (t + 1 < T) STAGE(nxt, 0, 1, t + 1);
        wg_barrier(); // B
        // S1: q01 (aLo x b23); read aHi(t); stage Bh0(t+2)
        MFMA_Q(0, aLo, 2);
        RD_AHI(cur);
        if (t + 2 < T) STAGE(cur, 1, 0, t + 2);
        wg_barrier(); // C
        // S2: q10 (aHi x b01); vmcnt(tile t+1 arrived); stage Bh1+Ah0(t+2)
        MFMA_Q(4, aHi, 0);
        if (t + 2 < T) {
            asm volatile("s_waitcnt vmcnt(2)" ::: "memory");
            STAGE(cur, 1, 1, t + 2);
            STAGE(cur, 0, 0, t + 2);
        } else if (t + 1 < T) {
            asm volatile("s_waitcnt vmcnt(0)" ::: "memory");
        }
        wg_barrier(); // D (all waves passed vmcnt -> t+1 LDS globally valid)
        // S3: q11 (aHi x b23); read aLo(t+1)+b01(t+1) from nxt
        MFMA_Q(4, aHi, 2);
        if (t + 1 < T) {
            RD_ALO(nxt);
            RD_B01(nxt);
        }
    }
#undef STAGE
#undef LDA
#undef LDB
#undef RD_ALO
#undef RD_AHI
#undef RD_B01
#undef RD_B23
#undef MFMA_Q

    asm volatile("s_waitcnt vmcnt(0)" ::: "memory");
    __syncthreads(); // main-loop LDS dead

    // ---- epilogue: per-wave LDS transpose [16][68] -> full-line bf16 stores ----
    float* eb = reinterpret_cast<float*>(&lds[0][0][0][0]) + wid * (16 * 68);
    const int erow = l >> 3, ec = l & 7;
    const int rowg = m0 + wm * 128;
    const int colg = n0 + wn * 64;
    float bv[4];
#pragma unroll
    for (int n = 0; n < 4; ++n) {
        if constexpr (MODE == 0) {
            const int col = colg + n * 16 + lr;
            int s = col >> 10;
            const float* bp = (s == 0) ? bias0 : ((s == 1) ? bias1 : bias2);
            bv[n] = bp[col & 1023];
        } else if constexpr (MODE == 2) {
            bv[n] = bias0[colg + n * 16 + lr];
        } else {
            bv[n] = 0.f;
        }
    }
    __hip_bfloat16* Cb = (MODE == 4)
        ? ((__hip_bfloat16*)Cout + (size_t)zb * zstride)
        : (__hip_bfloat16*)Cout;
#pragma unroll
    for (int m = 0; m < 8; ++m) {
#pragma unroll
        for (int n = 0; n < 4; ++n)
#pragma unroll
            for (int r = 0; r < 4; ++r) {
                float v = acc[m][n][r] + bv[n];
                if constexpr (MODE == 2) v = fmaxf(v, 0.f);
                eb[(lg * 4 + r) * 68 + n * 16 + lr] = v;
            }
#pragma unroll
        for (int i = 0; i < 2; ++i) {
            const int rr = erow + i * 8;
            float4 v0 = *reinterpret_cast<float4*>(&eb[rr * 68 + ec * 8]);
            float4 v1 = *reinterpret_cast<float4*>(&eb[rr * 68 + ec * 8 + 4]);
            uint4 o;
            o.x = cvt_pk_bf16(v0.x, v0.y);
            o.y = cvt_pk_bf16(v0.z, v0.w);
            o.z = cvt_pk_bf16(v1.x, v1.y);
            o.w = cvt_pk_bf16(v1.z, v1.w);
            *reinterpret_cast<uint4*>(&Cb[(size_t)(rowg + m * 16 + rr) * N + colg + ec * 8]) = o;
        }
        if constexpr (MODE == 0) {
            // fused V-transpose: V columns [2048,3072) -> vt[(b*16+h)*64+d][l]
            if (colg >= 2048) {
                const int h2 = (colg - 2048) >> 6;
                const int bh2 = ((rowg >> 10) << 4) + h2;
                const int l0 = (rowg & 1023) + m * 16;
                uint4 o0, o1;
                o0.x = cvt_pk_bf16(eb[0 * 68 + l], eb[1 * 68 + l]);
                o0.y = cvt_pk_bf16(eb[2 * 68 + l], eb[3 * 68 + l]);
                o0.z = cvt_pk_bf16(eb[4 * 68 + l], eb[5 * 68 + l]);
                o0.w = cvt_pk_bf16(eb[6 * 68 + l], eb[7 * 68 + l]);
                o1.x = cvt_pk_bf16(eb[8 * 68 + l], eb[9 * 68 + l]);
                o1.y = cvt_pk_bf16(eb[10 * 68 + l], eb[11 * 68 + l]);
                o1.z = cvt_pk_bf16(eb[12 * 68 + l], eb[13 * 68 + l]);
                o1.w = cvt_pk_bf16(eb[14 * 68 + l], eb[15 * 68 + l]);
                __hip_bfloat16* vrow = vtout + ((size_t)bh2 * 64 + l) * 1024 + l0;
                *reinterpret_cast<uint4*>(vrow) = o0;
                *reinterpret_cast<uint4*>(vrow + 8) = o1;
            }
        }
    }
}

// -------- flash attention v4: 32 q-rows/wave, swapped QK^T, in-register softmax --------
__global__ __launch_bounds__(512, 4) void attn4(const __hip_bfloat16* __restrict__ qkv,
                                                const __hip_bfloat16* __restrict__ vt,
                                                __hip_bfloat16* __restrict__ cat) {
    const int orig = blockIdx.y * 4 + blockIdx.x; // gridDim (4,128), nwg 512
    const int swz = (orig & 7) * 64 + (orig >> 3); // XCD -> 16 consecutive bh
    const int qt = swz & 3, bh = swz >> 2;
    const int b = bh >> 4, h = bh & 15;
    const int tid = threadIdx.x, w = tid >> 6, l = tid & 63;
    const int lr = l & 15, lg = l >> 4;
    const int sw = lr & 7;

    __shared__ __hip_bfloat16 Ks[2][64 * 64];
    __shared__ __hip_bfloat16 Vs[2][64 * 64];
    __shared__ __hip_bfloat16 plds[8][32 * 72];

    short8 qa[2][2];
#pragma unroll
    for (int q = 0; q < 2; ++q) {
        const size_t qrow = (size_t)(b * LL + qt * 256 + w * 32 + q * 16 + lr);
        qa[q][0] = *reinterpret_cast<const short8*>(qkv + qrow * 3072 + h * 64 + lg * 8);
        qa[q][1] = *reinterpret_cast<const short8*>(qkv + qrow * 3072 + h * 64 + 32 + lg * 8);
    }

    const int rA = tid >> 3, sA = (((tid & 7) ^ (rA & 7)) << 3);
    const __hip_bfloat16* kg = qkv + (size_t)(b * LL + rA) * 3072 + 1024 + h * 64 + sA;
    const __hip_bfloat16* vg = vt + ((size_t)bh * 64 + rA) * LL + sA;

#define STAGE_KV(bi, k0)                                        \
    do {                                                        \
        async_ld16(kg + (size_t)(k0) * 3072, &Ks[bi][w * 512]); \
        async_ld16(vg + (k0), &Vs[bi][w * 512]);                \
    } while (0)

    float mrun[2] = {-INFINITY, -INFINITY}, lrun[2] = {0.f, 0.f};
    f32x4 oacc[2][4];
#pragma unroll
    for (int q = 0; q < 2; ++q)
#pragma unroll
        for (int n = 0; n < 4; ++n) oacc[q][n] = (f32x4){0.f, 0.f, 0.f, 0.f};

    STAGE_KV(0, 0);
    asm volatile("s_waitcnt vmcnt(0)" ::: "memory");
    __syncthreads();

    const float SCALE = 0.18033688011112042f; // 1/sqrt(64) * log2(e)

    int cur = 0;
    for (int kt = 0; kt < 16; ++kt) {
        if (kt < 15) STAGE_KV(cur ^ 1, (kt + 1) * 64);

        f32x4 s[2][4];
#pragma unroll
        for (int m = 0; m < 4; ++m) {
            const int krow = m * 16 + lr;
            const short8 kf0 =
                *reinterpret_cast<const short8*>(&Ks[cur][krow * 64 + ((lg ^ sw) << 3)]);
            const short8 kf1 =
                *reinterpret_cast<const short8*>(&Ks[cur][krow * 64 + (((lg + 4) ^ sw) << 3)]);
#pragma unroll
            for (int q = 0; q < 2; ++q) {
                f32x4 t = (f32x4){0.f, 0.f, 0.f, 0.f};
                t = mfma16(kf0, qa[q][0], t);
                t = mfma16(kf1, qa[q][1], t);
                s[q][m] = t * SCALE;
            }
        }
        float smax[2];
#pragma unroll
        for (int q = 0; q < 2; ++q) {
            float mx = s[q][0][0];
#pragma unroll
            for (int m = 0; m < 4; ++m)
#pragma unroll
                for (int r = 0; r < 4; ++r) mx = fmaxf(mx, s[q][m][r]);
            mx = fmaxf(mx, __shfl_xor(mx, 16, 64));
            mx = fmaxf(mx, __shfl_xor(mx, 32, 64));
            smax[q] = mx;
        }
        if (__any(fmaxf(smax[0] - mrun[0], smax[1] - mrun[1]) > 8.0f)) {
#pragma unroll
            for (int q = 0; q < 2; ++q) {
                const float mnew = fmaxf(mrun[q], smax[q]);
                const float alpha = exp2_fast(mrun[q] - mnew);
                mrun[q] = mnew;
                lrun[q] *= alpha;
#pragma unroll
                for (int r = 0; r < 4; ++r) {
                    const float aD = __shfl(alpha, lg * 4 + r, 64);
#pragma unroll
                    for (int n = 0; n < 4; ++n) oacc[q][n][r] *= aD;
                }
            }
        }
#pragma unroll
        for (int q = 0; q < 2; ++q) {
            float tsum = 0.f;
#pragma unroll
            for (int m = 0; m < 4; ++m) {
                float p0 = exp2_fast(s[q][m][0] - mrun[q]);
                float p1 = exp2_fast(s[q][m][1] - mrun[q]);
                float p2 = exp2_fast(s[q][m][2] - mrun[q]);
                float p3 = exp2_fast(s[q][m][3] - mrun[q]);
                tsum += (p0 + p1) + (p2 + p3);
                uint2 d;
                d.x = cvt_pk_bf16(p0, p1);
                d.y = cvt_pk_bf16(p2, p3);
                *reinterpret_cast<uint2*>(&plds[w][(q * 16 + lr) * 72 + m * 16 + lg * 4]) = d;
            }
            tsum += __shfl_xor(tsum, 16, 64);
            tsum += __shfl_xor(tsum, 32, 64);
            lrun[q] += tsum;
        }
        asm volatile("s_waitcnt lgkmcnt(0)" ::: "memory");
        __builtin_amdgcn_sched_barrier(0);

        short8 pa[2][2];
#pragma unroll
        for (int q = 0; q < 2; ++q) {
            pa[q][0] = *reinterpret_cast<const short8*>(&plds[w][(q * 16 + lr) * 72 + lg * 8]);
            pa[q][1] =
                *reinterpret_cast<const short8*>(&plds[w][(q * 16 + lr) * 72 + 32 + lg * 8]);
        }
#pragma unroll
        for (int n = 0; n < 4; ++n) {
            const int vrow = n * 16 + lr;
            const short8 vf0 =
                *reinterpret_cast<const short8*>(&Vs[cur][vrow * 64 + ((lg ^ sw) << 3)]);
            const short8 vf1 =
                *reinterpret_cast<const short8*>(&Vs[cur][vrow * 64 + (((lg + 4) ^ sw) << 3)]);
#pragma unroll
            for (int q = 0; q < 2; ++q) {
                oacc[q][n] = mfma16(pa[q][0], vf0, oacc[q][n]);
                oacc[q][n] = mfma16(pa[q][1], vf1, oacc[q][n]);
            }
        }

        asm volatile("s_waitcnt vmcnt(0)" ::: "memory");
        __syncthreads();
        cur ^= 1;
    }
#undef STAGE_KV

#pragma unroll
    for (int q = 0; q < 2; ++q) {
        float rinv[4];
#pragma unroll
        for (int r = 0; r < 4; ++r) rinv[r] = 1.0f / __shfl(lrun[q], lg * 4 + r, 64);
#pragma unroll
        for (int n = 0; n < 4; ++n)
#pragma unroll
            for (int r = 0; r < 4; ++r) {
                const float v = oacc[q][n][r] * rinv[r];
                cat[(size_t)(b * LL + qt * 256 + w * 32 + q * 16 + lg * 4 + r) * EE + h * 64 +
                    n * 16 + lr] = __float2bfloat16(v);
            }
    }
}

// ------- fused split-K reduce (bf16 partials) + residual + bias + LayerNorm (E=1024) -------
template <bool CBF16, bool OUTF32>
__global__ __launch_bounds__(256) void ln_fused(const __hip_bfloat16* __restrict__ a,
                                                const __hip_bfloat16* __restrict__ b,
                                                const void* __restrict__ cv,
                                                const float* __restrict__ colbias,
                                                const float* __restrict__ gamma,
                                                const float* __restrict__ beta,
                                                void* __restrict__ outv) {
    const int row = blockIdx.x, tid = threadIdx.x;
    const size_t base = (size_t)row * EE;
    const ushort4 ua = reinterpret_cast<const ushort4*>(a + base)[tid];
    const ushort4 ub = reinterpret_cast<const ushort4*>(b + base)[tid];
    float4 z;
    if constexpr (CBF16) {
        const ushort4 uc =
            reinterpret_cast<const ushort4*>((const __hip_bfloat16*)cv + base)[tid];
        z.x = bf2f(uc.x); z.y = bf2f(uc.y); z.z = bf2f(uc.z); z.w = bf2f(uc.w);
    } else {
        z = reinterpret_cast<const float4*>((const float*)cv + base)[tid];
    }
    float4 cb = reinterpret_cast<const float4*>(colbias)[tid];
    float4 x;
    x.x = bf2f(ua.x) + bf2f(ub.x) + z.x + cb.x;
    x.y = bf2f(ua.y) + bf2f(ub.y) + z.y + cb.y;
    x.z = bf2f(ua.z) + bf2f(ub.z) + z.z + cb.z;
    x.w = bf2f(ua.w) + bf2f(ub.w) + z.w + cb.w;
    float s = x.x + x.y + x.z + x.w;
    float s2 = x.x * x.x + x.y * x.y + x.z * x.z + x.w * x.w;
#pragma unroll
    for (int msk = 1; msk < 64; msk <<= 1) {
        s += __shfl_xor(s, msk, 64);
        s2 += __shfl_xor(s2, msk, 64);
    }
    __shared__ float red[8];
    const int w = tid >> 6, l = tid & 63;
    if (l == 0) { red[w] = s; red[4 + w] = s2; }
    __syncthreads();
    s = red[0] + red[1] + red[2] + red[3];
    s2 = red[4] + red[5] + red[6] + red[7];
    const float mean = s * (1.f / 1024.f);
    const float var = s2 * (1.f / 1024.f) - mean * mean;
    const float rstd = rsqrtf(var + 1e-10f);
    float4 g = reinterpret_cast<const float4*>(gamma)[tid];
    float4 bt = reinterpret_cast<const float4*>(beta)[tid];
    float4 o;
    o.x = g.x * (x.x - mean) * rstd + bt.x;
    o.y = g.y * (x.y - mean) * rstd + bt.y;
    o.z = g.z * (x.z - mean) * rstd + bt.z;
    o.w = g.w * (x.w - mean) * rstd + bt.w;
    if constexpr (OUTF32) {
        reinterpret_cast<float4*>((float*)outv + base)[tid] = o;
    } else {
        ushort4 ob;
        ob.x = bf16bits(o.x); ob.y = bf16bits(o.y); ob.z = bf16bits(o.z); ob.w = bf16bits(o.w);
        reinterpret_cast<ushort4*>((__hip_bfloat16*)outv + base)[tid] = ob;
    }
}

extern "C" void kernel_launch(void* const* d_in, const int* in_sizes, int n_in,
                              void* d_out, int out_size, void* d_ws, size_t ws_size,
                              hipStream_t stream) {
    const float* x = (const float*)d_in[0];
    const float* Wq = (const float*)d_in[1];
    const float* bq = (const float*)d_in[2];
    const float* Wk = (const float*)d_in[3];
    const float* bk = (const float*)d_in[4];
    const float* Wv = (const float*)d_in[5];
    const float* bv = (const float*)d_in[6];
    const float* Wo = (const float*)d_in[7];
    const float* bo = (const float*)d_in[8];
    const float* W1 = (const float*)d_in[9];
    const float* b1 = (const float*)d_in[10];
    const float* W2 = (const float*)d_in[11];
    const float* b2 = (const float*)d_in[12];
    const float* gamma1 = (const float*)d_in[13];
    const float* beta1 = (const float*)d_in[14];
    const float* gamma2 = (const float*)d_in[15];
    const float* beta2 = (const float*)d_in[16];
    float* out = (float*)d_out;

    char* Wb = (char*)d_ws;
    const size_t MB = (size_t)1 << 20;
    if (ws_size < 168 * MB) return;
    __hip_bfloat16* xb = (__hip_bfloat16*)(Wb + 0 * MB);
    __hip_bfloat16* wqkvt = (__hip_bfloat16*)(Wb + 16 * MB);
    __hip_bfloat16* wot = (__hip_bfloat16*)(Wb + 22 * MB);
    __hip_bfloat16* w1t = (__hip_bfloat16*)(Wb + 24 * MB);
    __hip_bfloat16* w2t = (__hip_bfloat16*)(Wb + 32 * MB);
    __hip_bfloat16* qkvb = (__hip_bfloat16*)(Wb + 40 * MB);
    __hip_bfloat16* vtb = (__hip_bfloat16*)(Wb + 88 * MB);
    __hip_bfloat16* catb = (__hip_bfloat16*)(Wb + 104 * MB);
    __hip_bfloat16* p0 = (__hip_bfloat16*)(Wb + 40 * MB); // outproj bf16 partials (2x16MB)
    __hip_bfloat16* out2b = (__hip_bfloat16*)(Wb + 136 * MB);
    __hip_bfloat16* hbuf = (__hip_bfloat16*)(Wb + 40 * MB); // FFN1 out (64 MB)
    __hip_bfloat16* q0 = (__hip_bfloat16*)(Wb + 0 * MB);    // FFN2 bf16 partials (2x16MB)
    const size_t PSTRIDE = (size_t)8192 * 1024;             // bf16 elements (16 MB)

    // weights transpose + x conversion, one launch
    wtrans_all<<<5120, 256, 0, stream>>>(Wq, Wk, Wv, Wo, W1, W2, x, wqkvt, wot, w1t, w2t, xb);
    // QKV projection (+ fused V-transpose): grid 32x12, per-XCD cluster 8m x 6n
    gemm256<0, 8, 6, 0><<<dim3(32, 12, 1), 512, 0, stream>>>(xb, wqkvt, 8192, 3072, 1024, 1, 0,
                                                             qkvb, bq, bk, bv, vtb);
    // attention v4: 256 q-rows/block
    attn4<<<dim3(4, 128), 512, 0, stream>>>(qkvb, vtb, catb);
    // output projection: split-K=2; per-XCD cluster 8m x 4n, K-half from xcd
    gemm256<4, 8, 4, 1><<<dim3(32, 4, 2), 512, 0, stream>>>(catb, wot, 8192, 1024, 1024, 2,
                                                            PSTRIDE, p0, nullptr, nullptr,
                                                            nullptr, nullptr);
    // LN1 = LN(p0 + p1 + xb(bf16 residual) + bo) -> bf16 only (xb still live here)
    ln_fused<true, false><<<8192, 256, 0, stream>>>(p0, p0 + PSTRIDE, xb, bo, gamma1, beta1,
                                                    out2b);
    // FFN1 + ReLU: grid 32x16, per-XCD cluster 8m x 8n
    gemm256<2, 8, 8, 0><<<dim3(32, 16, 1), 512, 0, stream>>>(out2b, w1t, 8192, 4096, 1024, 1, 0,
                                                             hbuf, b1, nullptr, nullptr,
                                                             nullptr);
    // FFN2: split-K=2; per-XCD cluster 8m x 4n, K-half from xcd
    gemm256<4, 8, 4, 1><<<dim3(32, 4, 2), 512, 0, stream>>>(hbuf, w2t, 8192, 1024, 4096, 2,
                                                            PSTRIDE, q0, nullptr, nullptr,
                                                            nullptr, nullptr);
    // LN2 = LN(q0 + q1 + out2(bf16) + b2) -> d_out (f32)
    ln_fused<true, true><<<8192, 256, 0, stream>>>(q0, q0 + PSTRIDE, out2b, b2, gamma2, beta2,
                                                   out);
}

// Round 16
// 296.740 us; speedup vs baseline: 1.0293x; 1.0048x over previous
//
#include <hip/hip_runtime.h>
#include <hip/hip_bf16.h>

// Shapes (fixed per reference)
#define BB 8
#define LL 1024
#define EE 1024
#define HH 16
#define DHH 64
#define FFF 4096

typedef __attribute__((ext_vector_type(8))) short short8;
typedef __attribute__((ext_vector_type(4))) float f32x4;

__device__ inline f32x4 mfma16(short8 a, short8 b, f32x4 c) {
    return __builtin_amdgcn_mfma_f32_16x16x32_bf16(a, b, c, 0, 0, 0);
}

__device__ inline void async_ld16(const __hip_bfloat16* g, __hip_bfloat16* l) {
    __builtin_amdgcn_global_load_lds(
        (const __attribute__((address_space(1))) void*)g,
        (__attribute__((address_space(3))) void*)l, 16, 0, 0);
}

__device__ inline unsigned short bf16bits(float f) {
    __hip_bfloat16 h = __float2bfloat16(f);
    return *reinterpret_cast<unsigned short*>(&h);
}

__device__ inline float bf2f(unsigned short u) {
    unsigned v = ((unsigned)u) << 16;
    return *reinterpret_cast<float*>(&v);
}

__device__ inline float exp2_fast(float x) {
    float r;
    asm("v_exp_f32 %0, %1" : "=v"(r) : "v"(x));
    return r;
}

__device__ inline unsigned cvt_pk_bf16(float lo, float hi) {
    unsigned r;
    asm("v_cvt_pk_bf16_f32 %0, %1, %2" : "=v"(r) : "v"(lo), "v"(hi));
    return r;
}

// raw workgroup barrier, memory-fenced, no sched pins (m141: pinning hurts)
__device__ inline void wg_barrier() {
    asm volatile("" ::: "memory");
    __builtin_amdgcn_s_barrier();
    asm volatile("" ::: "memory");
}

// ------ fused weight transpose+convert (all 6 weights) + x f32->bf16 (one launch) ------
__global__ __launch_bounds__(256) void wtrans_all(
    const float* __restrict__ Wq, const float* __restrict__ Wk, const float* __restrict__ Wv,
    const float* __restrict__ Wo, const float* __restrict__ W1, const float* __restrict__ W2,
    const float* __restrict__ x,
    __hip_bfloat16* __restrict__ wqkvt, __hip_bfloat16* __restrict__ wot,
    __hip_bfloat16* __restrict__ w1t, __hip_bfloat16* __restrict__ w2t,
    __hip_bfloat16* __restrict__ xb) {
    const int id = blockIdx.x;
    const int tid = threadIdx.x;
    if (id >= 3072) { // x conversion: 2048 blocks x 1024 float4
        const int xi = id - 3072;
#pragma unroll
        for (int j = 0; j < 4; ++j) {
            const size_t f4 = (size_t)xi * 1024 + j * 256 + tid;
            float4 v = reinterpret_cast<const float4*>(x)[f4];
            ushort4 o;
            o.x = bf16bits(v.x); o.y = bf16bits(v.y); o.z = bf16bits(v.z); o.w = bf16bits(v.w);
            reinterpret_cast<ushort4*>(xb)[f4] = o;
        }
        return;
    }
    const float* src;
    __hip_bfloat16* dst;
    int K, N, k0, n0;
    if (id < 768) { // Wq/Wk/Wv: per-head [1024,64] -> [64,1024], 256 blocks each
        const int which = id >> 8, r = id & 255;
        const int z = r >> 4, xx = r & 15;
        src = ((which == 0) ? Wq : (which == 1) ? Wk : Wv) + (size_t)z * 65536;
        dst = wqkvt + (size_t)which * 1024 * 1024 + (size_t)z * 65536;
        K = 1024; N = 64; k0 = xx * 64; n0 = 0;
    } else if (id < 1024) { // Wo [1024,1024]
        const int r = id - 768;
        src = Wo; dst = wot; K = 1024; N = 1024; k0 = (r & 15) * 64; n0 = (r >> 4) * 64;
    } else if (id < 2048) { // W1 [1024,4096]
        const int r = id - 1024;
        src = W1; dst = w1t; K = 1024; N = 4096; k0 = (r & 15) * 64; n0 = (r >> 4) * 64;
    } else { // W2 [4096,1024]
        const int r = id - 2048;
        src = W2; dst = w2t; K = 4096; N = 1024; k0 = (r & 63) * 64; n0 = (r >> 6) * 64;
    }
    __shared__ __hip_bfloat16 t[64 * 66];
#pragma unroll
    for (int i = 0; i < 16; ++i) {
        int idx = tid + i * 256;
        int kr = idx >> 6, nc = idx & 63;
        t[kr * 66 + nc] = __float2bfloat16(src[(size_t)(k0 + kr) * N + n0 + nc]);
    }
    __syncthreads();
#pragma unroll
    for (int i = 0; i < 16; ++i) {
        int idx = tid + i * 256;
        int nr = idx >> 6, kc = idx & 63;
        dst[(size_t)(n0 + nr) * K + k0 + kc] = t[kc * 66 + nr];
    }
}

// ========== 256x256 GEMM, 8 waves x 128x64, read-ahead single-barrier phases ==========
// MODE 0: bf16 out + 3-range bias (QKV) + fused V-transpose into vtout.
// MODE 2: bf16 out + bias + relu. MODE 4: bf16 PARTIAL out (split-K).
// launch_bounds(512,1): LDS (128KB) already limits to 1 block/CU, so the old
// min-2-blocks bound only capped VGPR at 128 (live state ~250) and strangled
// the scheduler's read-ahead. Same occupancy, double register budget.
template <int MODE, int CM, int CN, int ZX>
__global__ __launch_bounds__(512, 1) void gemm256(
    const __hip_bfloat16* __restrict__ A, const __hip_bfloat16* __restrict__ Bm,
    int M, int N, int K, int ksplit, size_t zstride, void* __restrict__ Cout,
    const float* __restrict__ bias0, const float* __restrict__ bias1,
    const float* __restrict__ bias2, __hip_bfloat16* __restrict__ vtout) {
    __shared__ __hip_bfloat16 lds[2][2][2][128 * 64]; // [buf][op A=0/B=1][half][r*64+e]
    const int flat = blockIdx.x + gridDim.x * (blockIdx.y + gridDim.y * blockIdx.z);
    const int xcd = flat & 7, rank = flat >> 3;
    const int mc = xcd & 3, hc = xcd >> 2;
    const int ml = rank / CN, nl = rank % CN;
    const int mb = mc * CM + ml;
    const int nb = ZX ? nl : (hc * CN + nl);
    const int zb = ZX ? hc : 0;
    const int m0 = mb * 256, n0 = nb * 256;
    const int tid = threadIdx.x;
    const int wid = tid >> 6, l = tid & 63;
    const int wm = wid >> 2, wn = wid & 3;
    const int lr = l & 15, lg = l >> 4;
    const int T = K / (64 * ksplit);
    const int kb = zb * T;

    const int c0 = tid, c1 = tid + 512;
    const int r0 = c0 >> 3, s0 = (((c0 & 7) ^ (r0 & 7)) << 3);
    const int r1 = c1 >> 3, s1 = (((c1 & 7) ^ (r1 & 7)) << 3);
    const int ldst0 = wid * 512;
    const int ldst1 = 4096 + wid * 512;

#define STAGE(bi, isb, half, kt)                                                             \
    do {                                                                                     \
        const __hip_bfloat16* _s = (isb) ? Bm : A;                                           \
        const int _br = ((isb) ? n0 : m0) + (half) * 128;                                    \
        __hip_bfloat16* _d = &lds[bi][isb][half][0];                                         \
        async_ld16(_s + (size_t)(_br + r0) * K + (size_t)(kb + (kt)) * 64 + s0, _d + ldst0); \
        async_ld16(_s + (size_t)(_br + r1) * K + (size_t)(kb + (kt)) * 64 + s1, _d + ldst1); \
    } while (0)

    f32x4 acc[8][4];
#pragma unroll
    for (int m = 0; m < 8; ++m)
#pragma unroll
        for (int n = 0; n < 4; ++n) acc[m][n] = (f32x4){0.f, 0.f, 0.f, 0.f};

    short8 aLo[4][2], aHi[4][2], bR[4][2];

#define LDA(dst, bi, m, kh)                                                          \
    do {                                                                             \
        const int _ra = (m) * 16 + lr;                                               \
        const int _sl = ((kh) * 4 + lg) ^ (_ra & 7);                                 \
        dst = *reinterpret_cast<const short8*>(&lds[bi][0][wm][_ra * 64 + _sl * 8]); \
    } while (0)
#define LDB(dst, bi, n, kh)                                                               \
    do {                                                                                  \
        const int _rb = (wn & 1) * 64 + (n) * 16 + lr;                                    \
        const int _sl = ((kh) * 4 + lg) ^ (_rb & 7);                                      \
        dst = *reinterpret_cast<const short8*>(&lds[bi][1][wn >> 1][_rb * 64 + _sl * 8]); \
    } while (0)

#define RD_ALO(bi)                      \
    _Pragma("unroll") for (int m = 0; m < 4; ++m) { \
        LDA(aLo[m][0], bi, m, 0);       \
        LDA(aLo[m][1], bi, m, 1);       \
    }
#define RD_AHI(bi)                      \
    _Pragma("unroll") for (int m = 0; m < 4; ++m) { \
        LDA(aHi[m][0], bi, m + 4, 0);   \
        LDA(aHi[m][1], bi, m + 4, 1);   \
    }
#define RD_B01(bi)                      \
    _Pragma("unroll") for (int n = 0; n < 2; ++n) { \
        LDB(bR[n][0], bi, n, 0);        \
        LDB(bR[n][1], bi, n, 1);        \
    }
#define RD_B23(bi)                      \
    _Pragma("unroll") for (int n = 2; n < 4; ++n) { \
        LDB(bR[n][0], bi, n, 0);        \
        LDB(bR[n][1], bi, n, 1);        \
    }
#define MFMA_Q(mbase, afr, nlo)                                            \
    __builtin_amdgcn_s_setprio(1);                                         \
    _Pragma("unroll") for (int m = 0; m < 4; ++m) {                        \
        _Pragma("unroll") for (int n = (nlo); n < (nlo) + 2; ++n) {        \
            acc[(mbase) + m][n] = mfma16(afr[m][0], bR[n][0], acc[(mbase) + m][n]); \
            acc[(mbase) + m][n] = mfma16(afr[m][1], bR[n][1], acc[(mbase) + m][n]); \
        }                                                                  \
    }                                                                      \
    __builtin_amdgcn_s_setprio(0);

    // prologue: tile0 (Bh0,Bh1,Ah0,Ah1) + tile1's Bh0,Bh1,Ah0 = 14 load-instrs
    STAGE(0, 1, 0, 0);
    STAGE(0, 1, 1, 0);
    STAGE(0, 0, 0, 0);
    STAGE(0, 0, 1, 0);
    if (T > 1) {
        STAGE(1, 1, 0, 1);
        STAGE(1, 1, 1, 1);
        STAGE(1, 0, 0, 1);
        asm volatile("s_waitcnt vmcnt(6)" ::: "memory"); // tile0 (oldest 8) done
    } else {
        asm volatile("s_waitcnt vmcnt(0)" ::: "memory");
    }
    wg_barrier();
    RD_ALO(0);
    RD_B01(0);

    for (int t = 0; t < T; ++t) {
        const int cur = t & 1, nxt = cur ^ 1;
        wg_barrier(); // A
        // S0: q00 (aLo x b01); read b23(t); stage Ah1(t+1)
        MFMA_Q(0, aLo, 0);
        RD_B23(cur);
        if (t + 1 < T) STAGE(nxt, 0, 1, t + 1);
        wg_barrier(); // B
        // S1: q01 (aLo x b23); read aHi(t); stage Bh0(t+2)
        MFMA_Q(0, aLo, 2);
        RD_AHI(cur);
        if (t + 2 < T) STAGE(cur, 1, 0, t + 2);
        wg_barrier(); // C
        // S2: q10 (aHi x b01); vmcnt(tile t+1 arrived); stage Bh1+Ah0(t+2)
        MFMA_Q(4, aHi, 0);
        if (t + 2 < T) {
            asm volatile("s_waitcnt vmcnt(2)" ::: "memory");
            STAGE(cur, 1, 1, t + 2);
            STAGE(cur, 0, 0, t + 2);
        } else if (t + 1 < T) {
            asm volatile("s_waitcnt vmcnt(0)" ::: "memory");
        }
        wg_barrier(); // D (all waves passed vmcnt -> t+1 LDS globally valid)
        // S3: q11 (aHi x b23); read aLo(t+1)+b01(t+1) from nxt
        MFMA_Q(4, aHi, 2);
        if (t + 1 < T) {
            RD_ALO(nxt);
            RD_B01(nxt);
        }
    }
#undef STAGE
#undef LDA
#undef LDB
#undef RD_ALO
#undef RD_AHI
#undef RD_B01
#undef RD_B23
#undef MFMA_Q

    asm volatile("s_waitcnt vmcnt(0)" ::: "memory");
    __syncthreads(); // main-loop LDS dead

    // ---- epilogue: per-wave LDS transpose [16][68] -> full-line bf16 stores ----
    float* eb = reinterpret_cast<float*>(&lds[0][0][0][0]) + wid * (16 * 68);
    const int erow = l >> 3, ec = l & 7;
    const int rowg = m0 + wm * 128;
    const int colg = n0 + wn * 64;
    float bv[4];
#pragma unroll
    for (int n = 0; n < 4; ++n) {
        if constexpr (MODE == 0) {
            const int col = colg + n * 16 + lr;
            int s = col >> 10;
            const float* bp = (s == 0) ? bias0 : ((s == 1) ? bias1 : bias2);
            bv[n] = bp[col & 1023];
        } else if constexpr (MODE == 2) {
            bv[n] = bias0[colg + n * 16 + lr];
        } else {
            bv[n] = 0.f;
        }
    }
    __hip_bfloat16* Cb = (MODE == 4)
        ? ((__hip_bfloat16*)Cout + (size_t)zb * zstride)
        : (__hip_bfloat16*)Cout;
#pragma unroll
    for (int m = 0; m < 8; ++m) {
#pragma unroll
        for (int n = 0; n < 4; ++n)
#pragma unroll
            for (int r = 0; r < 4; ++r) {
                float v = acc[m][n][r] + bv[n];
                if constexpr (MODE == 2) v = fmaxf(v, 0.f);
                eb[(lg * 4 + r) * 68 + n * 16 + lr] = v;
            }
#pragma unroll
        for (int i = 0; i < 2; ++i) {
            const int rr = erow + i * 8;
            float4 v0 = *reinterpret_cast<float4*>(&eb[rr * 68 + ec * 8]);
            float4 v1 = *reinterpret_cast<float4*>(&eb[rr * 68 + ec * 8 + 4]);
            uint4 o;
            o.x = cvt_pk_bf16(v0.x, v0.y);
            o.y = cvt_pk_bf16(v0.z, v0.w);
            o.z = cvt_pk_bf16(v1.x, v1.y);
            o.w = cvt_pk_bf16(v1.z, v1.w);
            *reinterpret_cast<uint4*>(&Cb[(size_t)(rowg + m * 16 + rr) * N + colg + ec * 8]) = o;
        }
        if constexpr (MODE == 0) {
            // fused V-transpose: V columns [2048,3072) -> vt[(b*16+h)*64+d][l]
            if (colg >= 2048) {
                const int h2 = (colg - 2048) >> 6;
                const int bh2 = ((rowg >> 10) << 4) + h2;
                const int l0 = (rowg & 1023) + m * 16;
                uint4 o0, o1;
                o0.x = cvt_pk_bf16(eb[0 * 68 + l], eb[1 * 68 + l]);
                o0.y = cvt_pk_bf16(eb[2 * 68 + l], eb[3 * 68 + l]);
                o0.z = cvt_pk_bf16(eb[4 * 68 + l], eb[5 * 68 + l]);
                o0.w = cvt_pk_bf16(eb[6 * 68 + l], eb[7 * 68 + l]);
                o1.x = cvt_pk_bf16(eb[8 * 68 + l], eb[9 * 68 + l]);
                o1.y = cvt_pk_bf16(eb[10 * 68 + l], eb[11 * 68 + l]);
                o1.z = cvt_pk_bf16(eb[12 * 68 + l], eb[13 * 68 + l]);
                o1.w = cvt_pk_bf16(eb[14 * 68 + l], eb[15 * 68 + l]);
                __hip_bfloat16* vrow = vtout + ((size_t)bh2 * 64 + l) * 1024 + l0;
                *reinterpret_cast<uint4*>(vrow) = o0;
                *reinterpret_cast<uint4*>(vrow + 8) = o1;
            }
        }
    }
}

// -------- flash attention v4: 32 q-rows/wave, swapped QK^T, in-register softmax --------
__global__ __launch_bounds__(512, 4) void attn4(const __hip_bfloat16* __restrict__ qkv,
                                                const __hip_bfloat16* __restrict__ vt,
                                                __hip_bfloat16* __restrict__ cat) {
    const int orig = blockIdx.y * 4 + blockIdx.x; // gridDim (4,128), nwg 512
    const int swz = (orig & 7) * 64 + (orig >> 3); // XCD -> 16 consecutive bh
    const int qt = swz & 3, bh = swz >> 2;
    const int b = bh >> 4, h = bh & 15;
    const int tid = threadIdx.x, w = tid >> 6, l = tid & 63;
    const int lr = l & 15, lg = l >> 4;
    const int sw = lr & 7;

    __shared__ __hip_bfloat16 Ks[2][64 * 64];
    __shared__ __hip_bfloat16 Vs[2][64 * 64];
    __shared__ __hip_bfloat16 plds[8][32 * 72];

    short8 qa[2][2];
#pragma unroll
    for (int q = 0; q < 2; ++q) {
        const size_t qrow = (size_t)(b * LL + qt * 256 + w * 32 + q * 16 + lr);
        qa[q][0] = *reinterpret_cast<const short8*>(qkv + qrow * 3072 + h * 64 + lg * 8);
        qa[q][1] = *reinterpret_cast<const short8*>(qkv + qrow * 3072 + h * 64 + 32 + lg * 8);
    }

    const int rA = tid >> 3, sA = (((tid & 7) ^ (rA & 7)) << 3);
    const __hip_bfloat16* kg = qkv + (size_t)(b * LL + rA) * 3072 + 1024 + h * 64 + sA;
    const __hip_bfloat16* vg = vt + ((size_t)bh * 64 + rA) * LL + sA;

#define STAGE_KV(bi, k0)                                        \
    do {                                                        \
        async_ld16(kg + (size_t)(k0) * 3072, &Ks[bi][w * 512]); \
        async_ld16(vg + (k0), &Vs[bi][w * 512]);                \
    } while (0)

    float mrun[2] = {-INFINITY, -INFINITY}, lrun[2] = {0.f, 0.f};
    f32x4 oacc[2][4];
#pragma unroll
    for (int q = 0; q < 2; ++q)
#pragma unroll
        for (int n = 0; n < 4; ++n) oacc[q][n] = (f32x4){0.f, 0.f, 0.f, 0.f};

    STAGE_KV(0, 0);
    asm volatile("s_waitcnt vmcnt(0)" ::: "memory");
    __syncthreads();

    const float SCALE = 0.18033688011112042f; // 1/sqrt(64) * log2(e)

    int cur = 0;
    for (int kt = 0; kt < 16; ++kt) {
        if (kt < 15) STAGE_KV(cur ^ 1, (kt + 1) * 64);

        f32x4 s[2][4];
#pragma unroll
        for (int m = 0; m < 4; ++m) {
            const int krow = m * 16 + lr;
            const short8 kf0 =
                *reinterpret_cast<const short8*>(&Ks[cur][krow * 64 + ((lg ^ sw) << 3)]);
            const short8 kf1 =
                *reinterpret_cast<const short8*>(&Ks[cur][krow * 64 + (((lg + 4) ^ sw) << 3)]);
#pragma unroll
            for (int q = 0; q < 2; ++q) {
                f32x4 t = (f32x4){0.f, 0.f, 0.f, 0.f};
                t = mfma16(kf0, qa[q][0], t);
                t = mfma16(kf1, qa[q][1], t);
                s[q][m] = t * SCALE;
            }
        }
        float smax[2];
#pragma unroll
        for (int q = 0; q < 2; ++q) {
            float mx = s[q][0][0];
#pragma unroll
            for (int m = 0; m < 4; ++m)
#pragma unroll
                for (int r = 0; r < 4; ++r) mx = fmaxf(mx, s[q][m][r]);
            mx = fmaxf(mx, __shfl_xor(mx, 16, 64));
            mx = fmaxf(mx, __shfl_xor(mx, 32, 64));
            smax[q] = mx;
        }
        if (__any(fmaxf(smax[0] - mrun[0], smax[1] - mrun[1]) > 8.0f)) {
#pragma unroll
            for (int q = 0; q < 2; ++q) {
                const float mnew = fmaxf(mrun[q], smax[q]);
                const float alpha = exp2_fast(mrun[q] - mnew);
                mrun[q] = mnew;
                lrun[q] *= alpha;
#pragma unroll
                for (int r = 0; r < 4; ++r) {
                    const float aD = __shfl(alpha, lg * 4 + r, 64);
#pragma unroll
                    for (int n = 0; n < 4; ++n) oacc[q][n][r] *= aD;
                }
            }
        }
#pragma unroll
        for (int q = 0; q < 2; ++q) {
            float tsum = 0.f;
#pragma unroll
            for (int m = 0; m < 4; ++m) {
                float p0 = exp2_fast(s[q][m][0] - mrun[q]);
                float p1 = exp2_fast(s[q][m][1] - mrun[q]);
                float p2 = exp2_fast(s[q][m][2] - mrun[q]);
                float p3 = exp2_fast(s[q][m][3] - mrun[q]);
                tsum += (p0 + p1) + (p2 + p3);
                uint2 d;
                d.x = cvt_pk_bf16(p0, p1);
                d.y = cvt_pk_bf16(p2, p3);
                *reinterpret_cast<uint2*>(&plds[w][(q * 16 + lr) * 72 + m * 16 + lg * 4]) = d;
            }
            tsum += __shfl_xor(tsum, 16, 64);
            tsum += __shfl_xor(tsum, 32, 64);
            lrun[q] += tsum;
        }
        asm volatile("s_waitcnt lgkmcnt(0)" ::: "memory");
        __builtin_amdgcn_sched_barrier(0);

        short8 pa[2][2];
#pragma unroll
        for (int q = 0; q < 2; ++q) {
            pa[q][0] = *reinterpret_cast<const short8*>(&plds[w][(q * 16 + lr) * 72 + lg * 8]);
            pa[q][1] =
                *reinterpret_cast<const short8*>(&plds[w][(q * 16 + lr) * 72 + 32 + lg * 8]);
        }
#pragma unroll
        for (int n = 0; n < 4; ++n) {
            const int vrow = n * 16 + lr;
            const short8 vf0 =
                *reinterpret_cast<const short8*>(&Vs[cur][vrow * 64 + ((lg ^ sw) << 3)]);
            const short8 vf1 =
                *reinterpret_cast<const short8*>(&Vs[cur][vrow * 64 + (((lg + 4) ^ sw) << 3)]);
#pragma unroll
            for (int q = 0; q < 2; ++q) {
                oacc[q][n] = mfma16(pa[q][0], vf0, oacc[q][n]);
                oacc[q][n] = mfma16(pa[q][1], vf1, oacc[q][n]);
            }
        }

        asm volatile("s_waitcnt vmcnt(0)" ::: "memory");
        __syncthreads();
        cur ^= 1;
    }
#undef STAGE_KV

#pragma unroll
    for (int q = 0; q < 2; ++q) {
        float rinv[4];
#pragma unroll
        for (int r = 0; r < 4; ++r) rinv[r] = 1.0f / __shfl(lrun[q], lg * 4 + r, 64);
#pragma unroll
        for (int n = 0; n < 4; ++n)
#pragma unroll
            for (int r = 0; r < 4; ++r) {
                const float v = oacc[q][n][r] * rinv[r];
                cat[(size_t)(b * LL + qt * 256 + w * 32 + q * 16 + lg * 4 + r) * EE + h * 64 +
                    n * 16 + lr] = __float2bfloat16(v);
            }
    }
}

// ------- fused split-K reduce (bf16 partials) + residual + bias + LayerNorm (E=1024) -------
template <bool CBF16, bool OUTF32>
__global__ __launch_bounds__(256) void ln_fused(const __hip_bfloat16* __restrict__ a,
                                                const __hip_bfloat16* __restrict__ b,
                                                const void* __restrict__ cv,
                                                const float* __restrict__ colbias,
                                                const float* __restrict__ gamma,
                                                const float* __restrict__ beta,
                                                void* __restrict__ outv) {
    const int row = blockIdx.x, tid = threadIdx.x;
    const size_t base = (size_t)row * EE;
    const ushort4 ua = reinterpret_cast<const ushort4*>(a + base)[tid];
    const ushort4 ub = reinterpret_cast<const ushort4*>(b + base)[tid];
    float4 z;
    if constexpr (CBF16) {
        const ushort4 uc =
            reinterpret_cast<const ushort4*>((const __hip_bfloat16*)cv + base)[tid];
        z.x = bf2f(uc.x); z.y = bf2f(uc.y); z.z = bf2f(uc.z); z.w = bf2f(uc.w);
    } else {
        z = reinterpret_cast<const float4*>((const float*)cv + base)[tid];
    }
    float4 cb = reinterpret_cast<const float4*>(colbias)[tid];
    float4 x;
    x.x = bf2f(ua.x) + bf2f(ub.x) + z.x + cb.x;
    x.y = bf2f(ua.y) + bf2f(ub.y) + z.y + cb.y;
    x.z = bf2f(ua.z) + bf2f(ub.z) + z.z + cb.z;
    x.w = bf2f(ua.w) + bf2f(ub.w) + z.w + cb.w;
    float s = x.x + x.y + x.z + x.w;
    float s2 = x.x * x.x + x.y * x.y + x.z * x.z + x.w * x.w;
#pragma unroll
    for (int msk = 1; msk < 64; msk <<= 1) {
        s += __shfl_xor(s, msk, 64);
        s2 += __shfl_xor(s2, msk, 64);
    }
    __shared__ float red[8];
    const int w = tid >> 6, l = tid & 63;
    if (l == 0) { red[w] = s; red[4 + w] = s2; }
    __syncthreads();
    s = red[0] + red[1] + red[2] + red[3];
    s2 = red[4] + red[5] + red[6] + red[7];
    const float mean = s * (1.f / 1024.f);
    const float var = s2 * (1.f / 1024.f) - mean * mean;
    const float rstd = rsqrtf(var + 1e-10f);
    float4 g = reinterpret_cast<const float4*>(gamma)[tid];
    float4 bt = reinterpret_cast<const float4*>(beta)[tid];
    float4 o;
    o.x = g.x * (x.x - mean) * rstd + bt.x;
    o.y = g.y * (x.y - mean) * rstd + bt.y;
    o.z = g.z * (x.z - mean) * rstd + bt.z;
    o.w = g.w * (x.w - mean) * rstd + bt.w;
    if constexpr (OUTF32) {
        reinterpret_cast<float4*>((float*)outv + base)[tid] = o;
    } else {
        ushort4 ob;
        ob.x = bf16bits(o.x); ob.y = bf16bits(o.y); ob.z = bf16bits(o.z); ob.w = bf16bits(o.w);
        reinterpret_cast<ushort4*>((__hip_bfloat16*)outv + base)[tid] = ob;
    }
}

extern "C" void kernel_launch(void* const* d_in, const int* in_sizes, int n_in,
                              void* d_out, int out_size, void* d_ws, size_t ws_size,
                              hipStream_t stream) {
    const float* x = (const float*)d_in[0];
    const float* Wq = (const float*)d_in[1];
    const float* bq = (const float*)d_in[2];
    const float* Wk = (const float*)d_in[3];
    const float* bk = (const float*)d_in[4];
    const float* Wv = (const float*)d_in[5];
    const float* bv = (const float*)d_in[6];
    const float* Wo = (const float*)d_in[7];
    const float* bo = (const float*)d_in[8];
    const float* W1 = (const float*)d_in[9];
    const float* b1 = (const float*)d_in[10];
    const float* W2 = (const float*)d_in[11];
    const float* b2 = (const float*)d_in[12];
    const float* gamma1 = (const float*)d_in[13];
    const float* beta1 = (const float*)d_in[14];
    const float* gamma2 = (const float*)d_in[15];
    const float* beta2 = (const float*)d_in[16];
    float* out = (float*)d_out;

    char* Wb = (char*)d_ws;
    const size_t MB = (size_t)1 << 20;
    if (ws_size < 168 * MB) return;
    __hip_bfloat16* xb = (__hip_bfloat16*)(Wb + 0 * MB);
    __hip_bfloat16* wqkvt = (__hip_bfloat16*)(Wb + 16 * MB);
    __hip_bfloat16* wot = (__hip_bfloat16*)(Wb + 22 * MB);
    __hip_bfloat16* w1t = (__hip_bfloat16*)(Wb + 24 * MB);
    __hip_bfloat16* w2t = (__hip_bfloat16*)(Wb + 32 * MB);
    __hip_bfloat16* qkvb = (__hip_bfloat16*)(Wb + 40 * MB);
    __hip_bfloat16* vtb = (__hip_bfloat16*)(Wb + 88 * MB);
    __hip_bfloat16* catb = (__hip_bfloat16*)(Wb + 104 * MB);
    __hip_bfloat16* p0 = (__hip_bfloat16*)(Wb + 40 * MB); // outproj bf16 partials (2x16MB)
    __hip_bfloat16* out2b = (__hip_bfloat16*)(Wb + 136 * MB);
    __hip_bfloat16* hbuf = (__hip_bfloat16*)(Wb + 40 * MB); // FFN1 out (64 MB)
    __hip_bfloat16* q0 = (__hip_bfloat16*)(Wb + 0 * MB);    // FFN2 bf16 partials (2x16MB)
    const size_t PSTRIDE = (size_t)8192 * 1024;             // bf16 elements (16 MB)

    // weights transpose + x conversion, one launch
    wtrans_all<<<5120, 256, 0, stream>>>(Wq, Wk, Wv, Wo, W1, W2, x, wqkvt, wot, w1t, w2t, xb);
    // QKV projection (+ fused V-transpose): grid 32x12, per-XCD cluster 8m x 6n
    gemm256<0, 8, 6, 0><<<dim3(32, 12, 1), 512, 0, stream>>>(xb, wqkvt, 8192, 3072, 1024, 1, 0,
                                                             qkvb, bq, bk, bv, vtb);
    // attention v4: 256 q-rows/block
    attn4<<<dim3(4, 128), 512, 0, stream>>>(qkvb, vtb, catb);
    // output projection: split-K=2; per-XCD cluster 8m x 4n, K-half from xcd
    gemm256<4, 8, 4, 1><<<dim3(32, 4, 2), 512, 0, stream>>>(catb, wot, 8192, 1024, 1024, 2,
                                                            PSTRIDE, p0, nullptr, nullptr,
                                                            nullptr, nullptr);
    // LN1 = LN(p0 + p1 + xb(bf16 residual) + bo) -> bf16 only (xb still live here)
    ln_fused<true, false><<<8192, 256, 0, stream>>>(p0, p0 + PSTRIDE, xb, bo, gamma1, beta1,
                                                    out2b);
    // FFN1 + ReLU: grid 32x16, per-XCD cluster 8m x 8n
    gemm256<2, 8, 8, 0><<<dim3(32, 16, 1), 512, 0, stream>>>(out2b, w1t, 8192, 4096, 1024, 1, 0,
                                                             hbuf, b1, nullptr, nullptr,
                                                             nullptr);
    // FFN2: split-K=2; per-XCD cluster 8m x 4n, K-half from xcd
    gemm256<4, 8, 4, 1><<<dim3(32, 4, 2), 512, 0, stream>>>(hbuf, w2t, 8192, 1024, 4096, 2,
                                                            PSTRIDE, q0, nullptr, nullptr,
                                                            nullptr, nullptr);
    // LN2 = LN(q0 + q1 + out2(bf16) + b2) -> d_out (f32)
    ln_fused<true, true><<<8192, 256, 0, stream>>>(q0, q0 + PSTRIDE, out2b, b2, gamma2, beta2,
                                                   out);
}